// Round 2
// baseline (5554.614 us; speedup 1.0000x reference)
//
#include <hip/hip_runtime.h>
#include <hip/hip_bf16.h>

#define HEADS 8
#define DH 64
#define EMB 512
#define NP 4352
#define NTOK 4097
#define PADF 255
#define LM 256
#define SCALE 0.125f

// ---------------- generic tiled GEMM, fp32 accum ----------------
// C = alpha*A@B (+bias) (+relu); mode 1: C[gm-rowoff] += v (rows<rowoff dropped)
// batch z: off = (z/nh)*s?b + (z%nh)*s?h
__global__ void k_gemm_nn(const float* __restrict__ A, const float* __restrict__ B, float* __restrict__ C,
    int M,int N,int K,int lda,int ldb,int ldc,
    long sAb,long sAh,long sBb,long sBh,long sCb,long sCh,int nh,
    float alpha, const float* __restrict__ bias, int relu, int mode, int rowoff)
{
  int z = blockIdx.z;
  const float* Ab = A + (long)(z/nh)*sAb + (long)(z%nh)*sAh;
  const float* Bb = B + (long)(z/nh)*sBb + (long)(z%nh)*sBh;
  float* Cb = C + (long)(z/nh)*sCb + (long)(z%nh)*sCh;
  int m0 = blockIdx.y*64, n0 = blockIdx.x*64;
  __shared__ float As[16][65];
  __shared__ float Bs[16][65];
  int tid = threadIdx.x;
  int tx = tid & 15, ty = tid >> 4;
  float acc[4][4] = {};
  for(int k0=0;k0<K;k0+=16){
    #pragma unroll
    for(int i=0;i<4;i++){
      int idx = tid + i*256;
      int m = idx >> 4, kk = idx & 15;
      As[kk][m] = Ab[(long)(m0+m)*lda + (k0+kk)];
    }
    #pragma unroll
    for(int i=0;i<4;i++){
      int idx = tid + i*256;
      int n = idx & 63, kk = idx >> 6;
      Bs[kk][n] = Bb[(long)(k0+kk)*ldb + (n0+n)];
    }
    __syncthreads();
    #pragma unroll
    for(int kk=0;kk<16;kk++){
      float a[4], bv[4];
      #pragma unroll
      for(int i=0;i<4;i++) a[i]=As[kk][ty*4+i];
      #pragma unroll
      for(int j=0;j<4;j++) bv[j]=Bs[kk][tx*4+j];
      #pragma unroll
      for(int i=0;i<4;i++)
        #pragma unroll
        for(int j=0;j<4;j++) acc[i][j] += a[i]*bv[j];
    }
    __syncthreads();
  }
  #pragma unroll
  for(int i=0;i<4;i++){
    int gm = m0 + ty*4 + i;
    #pragma unroll
    for(int j=0;j<4;j++){
      int gn = n0 + tx*4 + j;
      float v = acc[i][j]*alpha;
      if(bias) v += bias[gn];
      if(relu) v = fmaxf(v, 0.0f);
      if(mode==0) Cb[(long)gm*ldc + gn] = v;
      else if(gm >= rowoff) Cb[(long)(gm-rowoff)*ldc + gn] += v;
    }
  }
}

// NT: B stored N x K row-major (ldb = K-stride). scores[i][j] = sum_k A[i,k]*B[j,k]
__global__ void k_gemm_nt(const float* __restrict__ A, const float* __restrict__ B, float* __restrict__ C,
    int M,int N,int K,int lda,int ldb,int ldc,
    long sAb,long sAh,long sBb,long sBh,long sCb,long sCh,int nh,
    float alpha)
{
  int z = blockIdx.z;
  const float* Ab = A + (long)(z/nh)*sAb + (long)(z%nh)*sAh;
  const float* Bb = B + (long)(z/nh)*sBb + (long)(z%nh)*sBh;
  float* Cb = C + (long)(z/nh)*sCb + (long)(z%nh)*sCh;
  int m0 = blockIdx.y*64, n0 = blockIdx.x*64;
  __shared__ float As[16][65];
  __shared__ float Bs[16][65];
  int tid = threadIdx.x;
  int tx = tid & 15, ty = tid >> 4;
  float acc[4][4] = {};
  for(int k0=0;k0<K;k0+=16){
    #pragma unroll
    for(int i=0;i<4;i++){
      int idx = tid + i*256;
      int m = idx >> 4, kk = idx & 15;
      As[kk][m] = Ab[(long)(m0+m)*lda + (k0+kk)];
    }
    #pragma unroll
    for(int i=0;i<4;i++){
      int idx = tid + i*256;
      int kk = idx & 15, n = idx >> 4;
      Bs[kk][n] = Bb[(long)(n0+n)*ldb + (k0+kk)];
    }
    __syncthreads();
    #pragma unroll
    for(int kk=0;kk<16;kk++){
      float a[4], bv[4];
      #pragma unroll
      for(int i=0;i<4;i++) a[i]=As[kk][ty*4+i];
      #pragma unroll
      for(int j=0;j<4;j++) bv[j]=Bs[kk][tx*4+j];
      #pragma unroll
      for(int i=0;i<4;i++)
        #pragma unroll
        for(int j=0;j<4;j++) acc[i][j] += a[i]*bv[j];
    }
    __syncthreads();
  }
  #pragma unroll
  for(int i=0;i<4;i++){
    int gm = m0 + ty*4 + i;
    #pragma unroll
    for(int j=0;j<4;j++){
      int gn = n0 + tx*4 + j;
      Cb[(long)gm*ldc + gn] = acc[i][j]*alpha;
    }
  }
}

// cls token row
__global__ void k_cls(const float* __restrict__ cls, float* __restrict__ seq){
  int b = blockIdx.x;
  seq[(long)b*NTOK*EMB + threadIdx.x] = cls[threadIdx.x];
}

// LayerNorm of seq (b,4097,512) into xp (b,4352,512) with 255 zero rows at front
__global__ void k_ln_pad(const float* __restrict__ seq, float* __restrict__ xp,
                         const float* __restrict__ g, const float* __restrict__ bb){
  int b = blockIdx.y, i = blockIdx.x, tid = threadIdx.x;
  float* out = xp + ((long)b*NP + i)*EMB;
  if(i < PADF){ out[tid]=0.0f; out[tid+256]=0.0f; return; }
  const float* x = seq + ((long)b*NTOK + (i-PADF))*EMB;
  float v0 = x[tid], v1 = x[tid+256];
  __shared__ float red[256];
  red[tid]=v0+v1; __syncthreads();
  for(int s=128;s>0;s>>=1){ if(tid<s) red[tid]+=red[tid+s]; __syncthreads(); }
  float mu = red[0]*(1.0f/512.0f); __syncthreads();
  float d0=v0-mu, d1=v1-mu;
  red[tid]=d0*d0+d1*d1; __syncthreads();
  for(int s=128;s>0;s>>=1){ if(tid<s) red[tid]+=red[tid+s]; __syncthreads(); }
  float rstd = rsqrtf(red[0]*(1.0f/512.0f) + 1e-5f);
  out[tid]     = d0*rstd*g[tid]     + bb[tid];
  out[tid+256] = d1*rstd*g[tid+256] + bb[tid+256];
}

// landmark means: q_l (scaled), k_l from qkv buffer
__global__ void k_landmarks(const float* __restrict__ qkv, float* __restrict__ q_l, float* __restrict__ k_l){
  int j = blockIdx.x, h = blockIdx.y, b = blockIdx.z, d = threadIdx.x;
  const float* base = qkv + (long)b*NP*1536 + h*64 + d;
  float sq=0.f, sk=0.f;
  for(int l=0;l<17;l++){
    long row = (long)(j*17+l)*1536;
    sq += base[row];
    sk += base[row+512];
  }
  long o = (((long)b*HEADS + h)*LM + j)*DH + d;
  q_l[o] = sq * (SCALE/17.0f);
  k_l[o] = sk * (1.0f/17.0f);
}

// row softmax in place
__global__ void k_softmax(float* __restrict__ X, int cols, int ld){
  long row = blockIdx.x;
  float* p = X + row*(long)ld;
  int tid = threadIdx.x;
  __shared__ float red[256];
  float mx = -1e30f;
  for(int j=tid;j<cols;j+=256) mx = fmaxf(mx, p[j]);
  red[tid]=mx; __syncthreads();
  for(int s=128;s>0;s>>=1){ if(tid<s) red[tid]=fmaxf(red[tid],red[tid+s]); __syncthreads(); }
  mx = red[0]; __syncthreads();
  float sum=0.f;
  for(int j=tid;j<cols;j+=256){ float e = expf(p[j]-mx); p[j]=e; sum+=e; }
  red[tid]=sum; __syncthreads();
  for(int s=128;s>0;s>>=1){ if(tid<s) red[tid]+=red[tid+s]; __syncthreads(); }
  float inv = 1.0f/red[0];
  for(int j=tid;j<cols;j+=256) p[j] *= inv;
}

// pinv: per-matrix max row-sum / col-sum of |x|
__global__ void k_pinv_norm(const float* __restrict__ A2, float* __restrict__ rmax, float* __restrict__ cmax){
  int z = blockIdx.x, tid = threadIdx.x;
  const float* X = A2 + (long)z*65536;
  float rs=0.f, cs=0.f;
  for(int j=0;j<256;j++){ rs += fabsf(X[tid*256+j]); cs += fabsf(X[j*256+tid]); }
  __shared__ float r1[256], r2[256];
  r1[tid]=rs; r2[tid]=cs; __syncthreads();
  for(int s=128;s>0;s>>=1){ if(tid<s){ r1[tid]=fmaxf(r1[tid],r1[tid+s]); r2[tid]=fmaxf(r2[tid],r2[tid+s]); } __syncthreads(); }
  if(tid==0){ rmax[z]=r1[0]; cmax[z]=r2[0]; }
}

// Z0 = x^T / (global max rowsum * global max colsum)
__global__ void k_pinv_zinit(const float* __restrict__ A2, float* __restrict__ Z,
                             const float* __restrict__ rmax, const float* __restrict__ cmax){
  int i = blockIdx.x, z = blockIdx.y, tid = threadIdx.x;
  float rm=0.f, cm=0.f;
  for(int t=0;t<16;t++){ rm=fmaxf(rm,rmax[t]); cm=fmaxf(cm,cmax[t]); }
  float inv = 1.0f/(rm*cm);
  Z[(long)z*65536 + i*256 + tid] = A2[(long)z*65536 + tid*256 + i] * inv;
}

// Y = c*I - X   (16 x 256 x 256)
__global__ void k_isub(const float* __restrict__ X, float* __restrict__ Y, float c){
  long idx = (long)blockIdx.x*256 + threadIdx.x;
  int ij = (int)(idx & 65535);
  Y[idx] = c*((ij>>8)==(ij&255) ? 1.0f : 0.0f) - X[idx];
}

// depthwise conv over sequence: Q[b,i,h*64+d] += sum_t k[h,t]*v[b,i+t-16,h,d]
__global__ void k_res_conv(const float* __restrict__ qkv, const float* __restrict__ resk, float* __restrict__ Q){
  int i = blockIdx.x, h = blockIdx.y, b = blockIdx.z, d = threadIdx.x;
  const float* vbase = qkv + (long)b*NP*1536 + 1024 + h*64 + d;
  float acc=0.f;
  for(int t=0;t<33;t++){
    int p = i + t - 16;
    if(p>=0 && p<NP) acc += resk[h*33+t]*vbase[(long)p*1536];
  }
  Q[((long)b*NP + i)*EMB + h*64 + d] += acc;
}

// PPEG: out = f + dw7(f)+dw5(f)+dw3(f) on 64x64 grid of tokens 1..4096; token0 copied
__global__ void k_ppeg(const float* __restrict__ seq, float* __restrict__ out,
    const float* __restrict__ w7,const float* __restrict__ b7,
    const float* __restrict__ w5,const float* __restrict__ b5,
    const float* __restrict__ w3,const float* __restrict__ b3){
  int t = blockIdx.x, b = blockIdx.y;
  long robase = ((long)b*NTOK + t)*EMB;
  if(t==0){
    out[robase+threadIdx.x]     = seq[robase+threadIdx.x];
    out[robase+threadIdx.x+256] = seq[robase+threadIdx.x+256];
    return;
  }
  int y = (t-1)>>6, x = (t-1)&63;
  const float* sb = seq + (long)b*NTOK*EMB + EMB;
  for(int cc=0;cc<2;cc++){
    int ch = threadIdx.x + cc*256;
    float acc = sb[((long)(y*64+x))*EMB + ch] + b7[ch] + b5[ch] + b3[ch];
    for(int ky=0;ky<7;ky++){ int yy=y+ky-3; if(yy<0||yy>=64) continue;
      for(int kx=0;kx<7;kx++){ int xx=x+kx-3; if(xx<0||xx>=64) continue;
        acc += w7[ch*49+ky*7+kx]*sb[((long)(yy*64+xx))*EMB+ch]; } }
    for(int ky=0;ky<5;ky++){ int yy=y+ky-2; if(yy<0||yy>=64) continue;
      for(int kx=0;kx<5;kx++){ int xx=x+kx-2; if(xx<0||xx>=64) continue;
        acc += w5[ch*25+ky*5+kx]*sb[((long)(yy*64+xx))*EMB+ch]; } }
    for(int ky=0;ky<3;ky++){ int yy=y+ky-1; if(yy<0||yy>=64) continue;
      for(int kx=0;kx<3;kx++){ int xx=x+kx-1; if(xx<0||xx>=64) continue;
        acc += w3[ch*9+ky*3+kx]*sb[((long)(yy*64+xx))*EMB+ch]; } }
    out[robase+ch] = acc;
  }
}

__global__ void k_final_ln(const float* __restrict__ seq, const float* __restrict__ g,
                           const float* __restrict__ bb, float* __restrict__ out){
  int b = blockIdx.x, tid = threadIdx.x;
  const float* x = seq + (long)b*NTOK*EMB;
  float v0 = x[tid], v1 = x[tid+256];
  __shared__ float red[256];
  red[tid]=v0+v1; __syncthreads();
  for(int s=128;s>0;s>>=1){ if(tid<s) red[tid]+=red[tid+s]; __syncthreads(); }
  float mu = red[0]*(1.0f/512.0f); __syncthreads();
  float d0=v0-mu, d1=v1-mu;
  red[tid]=d0*d0+d1*d1; __syncthreads();
  for(int s=128;s>0;s>>=1){ if(tid<s) red[tid]+=red[tid+s]; __syncthreads(); }
  float rstd = rsqrtf(red[0]*(1.0f/512.0f) + 1e-5f);
  out[b*512+tid]     = d0*rstd*g[tid]     + bb[tid];
  out[b*512+tid+256] = d1*rstd*g[tid+256] + bb[tid+256];
}

// ---------------- host ----------------
static inline void gnn(hipStream_t st, const float* A,const float* B,float* C,
  int M,int N,int K,int lda,int ldb,int ldc,
  long sAb,long sAh,long sBb,long sBh,long sCb,long sCh,int nh,int nb,
  float alpha,const float* bias,int relu,int mode,int rowoff){
  k_gemm_nn<<<dim3(N/64,M/64,nb),256,0,st>>>(A,B,C,M,N,K,lda,ldb,ldc,
      sAb,sAh,sBb,sBh,sCb,sCh,nh,alpha,bias,relu,mode,rowoff);
}
static inline void gnt(hipStream_t st, const float* A,const float* B,float* C,
  int M,int N,int K,int lda,int ldb,int ldc,
  long sAb,long sAh,long sBb,long sBh,long sCb,long sCh,int nh,int nb,float alpha){
  k_gemm_nt<<<dim3(N/64,M/64,nb),256,0,st>>>(A,B,C,M,N,K,lda,ldb,ldc,
      sAb,sAh,sBb,sBh,sCb,sCh,nh,alpha);
}

extern "C" void kernel_launch(void* const* d_in, const int* in_sizes, int n_in,
                              void* d_out, int out_size, void* d_ws, size_t ws_size,
                              hipStream_t stream) {
  const float* in[24];
  for(int i=0;i<24;i++) in[i] = (const float*)d_in[i];

  float* W = (float*)d_ws;
  size_t off = 0;
  float* seqA = W+off; off += 2L*NTOK*EMB;
  float* seqB = W+off; off += 2L*NTOK*EMB;
  float* xp   = W+off; off += 2L*NP*EMB;
  float* qkvb = W+off; off += 2L*NP*1536;
  float* q_l  = W+off; off += 2L*HEADS*LM*DH;
  float* k_l  = W+off; off += 2L*HEADS*LM*DH;
  float* att2 = W+off; off += 16L*65536;
  float* Z0   = W+off; off += 16L*65536;
  float* Z1   = W+off; off += 16L*65536;
  float* XZ   = W+off; off += 16L*65536;
  float* Tm   = W+off; off += 16L*65536;
  float* Um   = W+off; off += 16L*65536;
  float* avb  = W+off; off += 16L*LM*DH;
  float* zav  = W+off; off += 16L*LM*DH;
  float* bigA = W+off; off += 16L*(long)LM*NP;
  float* Qc   = W+off; off += 2L*NP*EMB;
  float* rmax = W+off; off += 16;
  float* cmax = W+off; off += 16;
  if (ws_size < off*sizeof(float)) return;  // workspace too small — output stays 0, fails loudly

  // fc1: relu(h @ w_fc1 + b) directly into seqA tokens 1..4096
  gnn(stream, in[0], in[1], seqA+EMB, 4096,512,1024, 1024,512,512,
      4096L*1024,0, 0,0, (long)NTOK*EMB,0, 1,2, 1.0f, in[2], 1, 0, 0);
  k_cls<<<2,512,0,stream>>>(in[3], seqA);

  auto attention = [&](float* seq, const float* lng,const float* lnb,
                       const float* qkvw,const float* outw,const float* outb,const float* resk){
    k_ln_pad<<<dim3(NP,2),256,0,stream>>>(seq, xp, lng, lnb);
    gnn(stream, xp, qkvw, qkvb, NP,1536,512, 512,1536,1536,
        (long)NP*512,0, 0,0, (long)NP*1536,0, 1,2, 1.0f,nullptr,0,0,0);
    k_landmarks<<<dim3(LM,HEADS,2),64,0,stream>>>(qkvb, q_l, k_l);
    // attn2 = softmax(q_l @ k_l^T)
    gnt(stream, q_l, k_l, att2, LM,LM,DH, DH,DH,LM,
        16384,0, 16384,0, 65536,0, 1,16, 1.0f);
    k_softmax<<<16*LM,256,0,stream>>>(att2, LM, LM);
    // pinv(attn2) -> Z0
    k_pinv_norm<<<16,256,0,stream>>>(att2, rmax, cmax);
    k_pinv_zinit<<<dim3(LM,16),256,0,stream>>>(att2, Z0, rmax, cmax);
    for(int it=0; it<6; it++){
      float* zin  = (it&1)?Z1:Z0;
      float* zout = (it&1)?Z0:Z1;
      gnn(stream, att2, zin, XZ, LM,LM,LM, LM,LM,LM, 65536,0,65536,0,65536,0, 1,16, 1.0f,nullptr,0,0,0);
      k_isub<<<4096,256,0,stream>>>(XZ, Tm, 7.0f);
      gnn(stream, XZ, Tm, Um, LM,LM,LM, LM,LM,LM, 65536,0,65536,0,65536,0, 1,16, 1.0f,nullptr,0,0,0);
      k_isub<<<4096,256,0,stream>>>(Um, Tm, 15.0f);
      gnn(stream, XZ, Tm, Um, LM,LM,LM, LM,LM,LM, 65536,0,65536,0,65536,0, 1,16, 1.0f,nullptr,0,0,0);
      k_isub<<<4096,256,0,stream>>>(Um, Tm, 13.0f);
      gnn(stream, zin, Tm, zout, LM,LM,LM, LM,LM,LM, 65536,0,65536,0,65536,0, 1,16, 0.25f,nullptr,0,0,0);
    }
    // attn3 = softmax(q_l @ k^T); av = attn3 @ v
    gnt(stream, q_l, qkvb+512, bigA, LM,NP,DH, DH,1536,NP,
        8L*16384,16384, (long)NP*1536,64, 8L*LM*NP,(long)LM*NP, 8,16, 1.0f);
    k_softmax<<<16*LM,256,0,stream>>>(bigA, NP, NP);
    gnn(stream, bigA, qkvb+1024, avb, LM,DH,NP, NP,1536,DH,
        8L*LM*NP,(long)LM*NP, (long)NP*1536,64, 8L*16384,16384, 8,16, 1.0f,nullptr,0,0,0);
    // attn1 = softmax(SCALE * q @ k_l^T)  (reuse bigA)
    gnt(stream, qkvb, k_l, bigA, NP,LM,DH, 1536,DH,LM,
        (long)NP*1536,64, 8L*16384,16384, 8L*NP*LM,(long)NP*LM, 8,16, SCALE);
    k_softmax<<<16*NP,256,0,stream>>>(bigA, LM, LM);
    // out = attn1 @ (Z0 @ av)   (re-associated)
    gnn(stream, Z0, avb, zav, LM,DH,LM, LM,DH,DH, 65536,0, 16384,0, 16384,0, 1,16, 1.0f,nullptr,0,0,0);
    gnn(stream, bigA, zav, Qc, NP,DH,LM, LM,DH,EMB,
        8L*NP*LM,(long)NP*LM, 8L*16384,16384, (long)NP*EMB,64, 8,16, 1.0f,nullptr,0,0,0);
    // + depthwise residual conv on v
    k_res_conv<<<dim3(NP,HEADS,2),64,0,stream>>>(qkvb, resk, Qc);
    // out proj + residual add into seq (rows >= 255 map to tokens 0..4096)
    gnn(stream, Qc, outw, seq, NP,EMB,EMB, EMB,EMB,EMB,
        (long)NP*EMB,0, 0,0, (long)NTOK*EMB,0, 1,2, 1.0f, outb, 0, 1, PADF);
  };

  attention(seqA, in[4], in[5], in[6], in[7], in[8], in[9]);
  k_ppeg<<<dim3(NTOK,2),256,0,stream>>>(seqA, seqB, in[10],in[11],in[12],in[13],in[14],in[15]);
  attention(seqB, in[16], in[17], in[18], in[19], in[20], in[21]);
  k_final_ln<<<2,256,0,stream>>>(seqB, in[22], in[23], (float*)d_out);
}

// Round 3
// 2565.359 us; speedup vs baseline: 2.1652x; 2.1652x over previous
//
#include <hip/hip_runtime.h>
#include <hip/hip_bf16.h>

#define HEADS 8
#define DH 64
#define EMB 512
#define NP 4352
#define NTOK 4097
#define PADF 255
#define LM 256
#define SCALE 0.125f

typedef __attribute__((ext_vector_type(8))) short bf8;
typedef __attribute__((ext_vector_type(4))) float f4;

__device__ __forceinline__ unsigned short f2b(float f){
  union { float f; unsigned u; } x; x.f = f;
  unsigned r = x.u + 0x7fffu + ((x.u>>16)&1u);
  return (unsigned short)(r>>16);
}
__device__ __forceinline__ float b2f(unsigned short h){
  union { unsigned u; float f; } x; x.u = ((unsigned)h)<<16;
  return x.f;
}

// ---------------- bf16 MFMA GEMM ----------------
// C = alpha*A@B (+bias)(+relu)(+diagc*I); mode 1: C[gm-rowoff] += v (rows<rowoff dropped)
// A: fp32 [M][K] (lda). TB=0: B fp32 [K][N] (ldb); TB=1: B fp32 [N][K] (ldb).
// SPLIT=1: hi/lo bf16 decomposition (3 MFMAs) for ~fp16+ precision (pinv chain).
// Tile 64x64, BK=32, 256 threads = 4 waves; wave w -> rows 16w..16w+15.
template<int TB, int SPLIT>
__global__ __launch_bounds__(256)
void k_mf(const float* __restrict__ A, const float* __restrict__ B, float* __restrict__ C,
    int K,int lda,int ldb,int ldc,
    long sAb,long sAh,long sBb,long sBh,long sCb,long sCh,int nh,
    float alpha, const float* __restrict__ bias, int relu, int mode, int rowoff, float diagc)
{
  int z = blockIdx.z;
  const float* Ab = A + (long)(z/nh)*sAb + (long)(z%nh)*sAh;
  const float* Bb = B + (long)(z/nh)*sBb + (long)(z%nh)*sBh;
  float* Cb = C + (long)(z/nh)*sCb + (long)(z%nh)*sCh;
  int m0 = blockIdx.y*64, n0 = blockIdx.x*64;
  __shared__ unsigned short As[64*40];
  __shared__ unsigned short Bs[64*40];
  __shared__ unsigned short Al[SPLIT?64*40:1];
  __shared__ unsigned short Bl[SPLIT?64*40:1];
  int tid = threadIdx.x;
  int w = tid>>6, lane = tid&63, q = lane>>4, lr = lane&15;
  f4 acc[4] = {};
  for(int k0=0;k0<K;k0+=32){
    // stage A: [m][k], row padded to 40
    #pragma unroll
    for(int p=0;p<2;p++){
      int idx = tid + p*256;
      int m = idx>>3, kc = (idx&7)*4;
      float4 v = *(const float4*)&Ab[(long)(m0+m)*lda + k0 + kc];
      int o = m*40 + kc;
      unsigned short h0=f2b(v.x),h1=f2b(v.y),h2=f2b(v.z),h3=f2b(v.w);
      As[o]=h0; As[o+1]=h1; As[o+2]=h2; As[o+3]=h3;
      if(SPLIT){
        Al[o]  =f2b(v.x-b2f(h0)); Al[o+1]=f2b(v.y-b2f(h1));
        Al[o+2]=f2b(v.z-b2f(h2)); Al[o+3]=f2b(v.w-b2f(h3));
      }
    }
    // stage B -> LDS [n][k]
    if(TB){
      #pragma unroll
      for(int p=0;p<2;p++){
        int idx = tid + p*256;
        int n = idx>>3, kc = (idx&7)*4;
        float4 v = *(const float4*)&Bb[(long)(n0+n)*ldb + k0 + kc];
        int o = n*40 + kc;
        unsigned short h0=f2b(v.x),h1=f2b(v.y),h2=f2b(v.z),h3=f2b(v.w);
        Bs[o]=h0; Bs[o+1]=h1; Bs[o+2]=h2; Bs[o+3]=h3;
        if(SPLIT){
          Bl[o]  =f2b(v.x-b2f(h0)); Bl[o+1]=f2b(v.y-b2f(h1));
          Bl[o+2]=f2b(v.z-b2f(h2)); Bl[o+3]=f2b(v.w-b2f(h3));
        }
      }
    } else {
      #pragma unroll
      for(int p=0;p<2;p++){
        int idx = tid + p*256;
        int kk = idx>>4, n4 = (idx&15)*4;
        float4 v = *(const float4*)&Bb[(long)(k0+kk)*ldb + n0 + n4];
        unsigned short h0=f2b(v.x),h1=f2b(v.y),h2=f2b(v.z),h3=f2b(v.w);
        Bs[(n4  )*40+kk]=h0; Bs[(n4+1)*40+kk]=h1;
        Bs[(n4+2)*40+kk]=h2; Bs[(n4+3)*40+kk]=h3;
        if(SPLIT){
          Bl[(n4  )*40+kk]=f2b(v.x-b2f(h0)); Bl[(n4+1)*40+kk]=f2b(v.y-b2f(h1));
          Bl[(n4+2)*40+kk]=f2b(v.z-b2f(h2)); Bl[(n4+3)*40+kk]=f2b(v.w-b2f(h3));
        }
      }
    }
    __syncthreads();
    bf8 af = *(const bf8*)&As[(w*16+lr)*40 + q*8];
    bf8 al;
    if(SPLIT) al = *(const bf8*)&Al[(w*16+lr)*40 + q*8];
    #pragma unroll
    for(int t=0;t<4;t++){
      bf8 bf = *(const bf8*)&Bs[(t*16+lr)*40 + q*8];
      acc[t] = __builtin_amdgcn_mfma_f32_16x16x32_bf16(af, bf, acc[t], 0,0,0);
      if(SPLIT){
        bf8 bl = *(const bf8*)&Bl[(t*16+lr)*40 + q*8];
        acc[t] = __builtin_amdgcn_mfma_f32_16x16x32_bf16(af, bl, acc[t], 0,0,0);
        acc[t] = __builtin_amdgcn_mfma_f32_16x16x32_bf16(al, bf, acc[t], 0,0,0);
      }
    }
    __syncthreads();
  }
  #pragma unroll
  for(int t=0;t<4;t++){
    #pragma unroll
    for(int r=0;r<4;r++){
      int gm = m0 + w*16 + q*4 + r;
      int gn = n0 + t*16 + lr;
      float v = acc[t][r]*alpha;
      if(bias) v += bias[gn];
      if(diagc != 0.0f && gm==gn) v += diagc;
      if(relu) v = fmaxf(v,0.f);
      if(mode==0) Cb[(long)gm*ldc+gn] = v;
      else if(gm>=rowoff) Cb[(long)(gm-rowoff)*ldc+gn] += v;
    }
  }
}

// cls token row
__global__ void k_cls(const float* __restrict__ cls, float* __restrict__ seq){
  int b = blockIdx.x;
  seq[(long)b*NTOK*EMB + threadIdx.x] = cls[threadIdx.x];
}

// LayerNorm of seq (b,4097,512) into xp (b,4352,512) with 255 zero rows at front
__global__ void k_ln_pad(const float* __restrict__ seq, float* __restrict__ xp,
                         const float* __restrict__ g, const float* __restrict__ bb){
  int b = blockIdx.y, i = blockIdx.x, tid = threadIdx.x;
  float* out = xp + ((long)b*NP + i)*EMB;
  if(i < PADF){ out[tid]=0.0f; out[tid+256]=0.0f; return; }
  const float* x = seq + ((long)b*NTOK + (i-PADF))*EMB;
  float v0 = x[tid], v1 = x[tid+256];
  __shared__ float red[256];
  red[tid]=v0+v1; __syncthreads();
  for(int s=128;s>0;s>>=1){ if(tid<s) red[tid]+=red[tid+s]; __syncthreads(); }
  float mu = red[0]*(1.0f/512.0f); __syncthreads();
  float d0=v0-mu, d1=v1-mu;
  red[tid]=d0*d0+d1*d1; __syncthreads();
  for(int s=128;s>0;s>>=1){ if(tid<s) red[tid]+=red[tid+s]; __syncthreads(); }
  float rstd = rsqrtf(red[0]*(1.0f/512.0f) + 1e-5f);
  out[tid]     = d0*rstd*g[tid]     + bb[tid];
  out[tid+256] = d1*rstd*g[tid+256] + bb[tid+256];
}

// landmark means: q_l (scaled), k_l
__global__ void k_landmarks(const float* __restrict__ qkv, float* __restrict__ q_l, float* __restrict__ k_l){
  int j = blockIdx.x, h = blockIdx.y, b = blockIdx.z, d = threadIdx.x;
  const float* base = qkv + (long)b*NP*1536 + h*64 + d;
  float sq=0.f, sk=0.f;
  for(int l=0;l<17;l++){
    long row = (long)(j*17+l)*1536;
    sq += base[row];
    sk += base[row+512];
  }
  long o = (((long)b*HEADS + h)*LM + j)*DH + d;
  q_l[o] = sq * (SCALE/17.0f);
  k_l[o] = sk * (1.0f/17.0f);
}

// row softmax in place
__global__ void k_softmax(float* __restrict__ X, int cols, int ld){
  long row = blockIdx.x;
  float* p = X + row*(long)ld;
  int tid = threadIdx.x;
  __shared__ float red[256];
  float mx = -1e30f;
  for(int j=tid;j<cols;j+=256) mx = fmaxf(mx, p[j]);
  red[tid]=mx; __syncthreads();
  for(int s=128;s>0;s>>=1){ if(tid<s) red[tid]=fmaxf(red[tid],red[tid+s]); __syncthreads(); }
  mx = red[0]; __syncthreads();
  float sum=0.f;
  for(int j=tid;j<cols;j+=256){ float e = expf(p[j]-mx); p[j]=e; sum+=e; }
  red[tid]=sum; __syncthreads();
  for(int s=128;s>0;s>>=1){ if(tid<s) red[tid]+=red[tid+s]; __syncthreads(); }
  float inv = 1.0f/red[0];
  for(int j=tid;j<cols;j+=256) p[j] *= inv;
}

// pinv: per-matrix max row-sum / col-sum of |x|
__global__ void k_pinv_norm(const float* __restrict__ A2, float* __restrict__ rmax, float* __restrict__ cmax){
  int z = blockIdx.x, tid = threadIdx.x;
  const float* X = A2 + (long)z*65536;
  float rs=0.f, cs=0.f;
  for(int j=0;j<256;j++){ rs += fabsf(X[tid*256+j]); cs += fabsf(X[j*256+tid]); }
  __shared__ float r1[256], r2[256];
  r1[tid]=rs; r2[tid]=cs; __syncthreads();
  for(int s=128;s>0;s>>=1){ if(tid<s){ r1[tid]=fmaxf(r1[tid],r1[tid+s]); r2[tid]=fmaxf(r2[tid],r2[tid+s]); } __syncthreads(); }
  if(tid==0){ rmax[z]=r1[0]; cmax[z]=r2[0]; }
}

// Z0 = x^T / (global max rowsum * global max colsum)
__global__ void k_pinv_zinit(const float* __restrict__ A2, float* __restrict__ Z,
                             const float* __restrict__ rmax, const float* __restrict__ cmax){
  int i = blockIdx.x, z = blockIdx.y, tid = threadIdx.x;
  float rm=0.f, cm=0.f;
  for(int t=0;t<16;t++){ rm=fmaxf(rm,rmax[t]); cm=fmaxf(cm,cmax[t]); }
  float inv = 1.0f/(rm*cm);
  Z[(long)z*65536 + i*256 + tid] = A2[(long)z*65536 + tid*256 + i] * inv;
}

// Y = c*I - X
__global__ void k_isub(const float* __restrict__ X, float* __restrict__ Y, float c){
  long idx = (long)blockIdx.x*256 + threadIdx.x;
  int ij = (int)(idx & 65535);
  Y[idx] = c*((ij>>8)==(ij&255) ? 1.0f : 0.0f) - X[idx];
}

// depthwise conv over sequence: Q[b,i,h*64+d] += sum_t k[h,t]*v[b,i+t-16,h,d]
__global__ void k_res_conv(const float* __restrict__ qkv, const float* __restrict__ resk, float* __restrict__ Q){
  int i = blockIdx.x, h = blockIdx.y, b = blockIdx.z, d = threadIdx.x;
  const float* vbase = qkv + (long)b*NP*1536 + 1024 + h*64 + d;
  float acc=0.f;
  for(int t=0;t<33;t++){
    int p = i + t - 16;
    if(p>=0 && p<NP) acc += resk[h*33+t]*vbase[(long)p*1536];
  }
  Q[((long)b*NP + i)*EMB + h*64 + d] += acc;
}

// PPEG: weights staged in LDS; block = 128 ch x 2 rows; thread sweeps 64 x in chunks of 8
__global__ __launch_bounds__(256)
void k_ppeg(const float* __restrict__ seq, float* __restrict__ out,
    const float* __restrict__ w7,const float* __restrict__ b7,
    const float* __restrict__ w5,const float* __restrict__ b5,
    const float* __restrict__ w3,const float* __restrict__ b3){
  int b = blockIdx.z, cg = blockIdx.y, rp = blockIdx.x;
  int ch0 = cg*128;
  __shared__ float s7[128*49], s5[128*25], s3[128*9], sbias[128];
  int tid = threadIdx.x;
  for(int i=tid;i<128*49;i+=256) s7[i] = w7[ch0*49+i];
  for(int i=tid;i<128*25;i+=256) s5[i] = w5[ch0*25+i];
  for(int i=tid;i<128*9;i+=256)  s3[i] = w3[ch0*9+i];
  if(tid<128) sbias[tid] = b7[ch0+tid]+b5[ch0+tid]+b3[ch0+tid];
  if(cg==0 && rp==0){  // token 0 copy
    out[(long)b*NTOK*EMB + tid]       = seq[(long)b*NTOK*EMB + tid];
    out[(long)b*NTOK*EMB + 256 + tid] = seq[(long)b*NTOK*EMB + 256 + tid];
  }
  __syncthreads();
  int c = tid & 127;
  int y = rp*2 + (tid>>7);
  const float* sbase = seq + (long)b*NTOK*EMB + EMB + (ch0 + c);
  float* obase = out + (long)b*NTOK*EMB + EMB + (ch0 + c);
  const float* W7 = &s7[c*49];
  const float* W5 = &s5[c*25];
  const float* W3 = &s3[c*9];
  float bsum = sbias[c];
  for(int xc=0;xc<8;xc++){
    int xb = xc*8;
    float acc[8];
    #pragma unroll
    for(int j=0;j<8;j++) acc[j] = sbase[(long)(y*64+xb+j)*EMB] + bsum;
    #pragma unroll
    for(int dy=-3;dy<=3;dy++){
      int yy = y+dy;
      if(yy<0||yy>=64) continue;
      float v[14];
      #pragma unroll
      for(int u=0;u<14;u++){
        int xx = xb + u - 3;
        v[u] = (xx>=0 && xx<64) ? sbase[(long)(yy*64+xx)*EMB] : 0.f;
      }
      #pragma unroll
      for(int dx=-3;dx<=3;dx++){
        float wsum = W7[(dy+3)*7+(dx+3)];
        if(dy>=-2&&dy<=2&&dx>=-2&&dx<=2) wsum += W5[(dy+2)*5+(dx+2)];
        if(dy>=-1&&dy<=1&&dx>=-1&&dx<=1) wsum += W3[(dy+1)*3+(dx+1)];
        #pragma unroll
        for(int j=0;j<8;j++) acc[j] += v[j+dx+3]*wsum;
      }
    }
    #pragma unroll
    for(int j=0;j<8;j++) obase[(long)(y*64+xb+j)*EMB] = acc[j];
  }
}

__global__ void k_final_ln(const float* __restrict__ seq, const float* __restrict__ g,
                           const float* __restrict__ bb, float* __restrict__ out){
  int b = blockIdx.x, tid = threadIdx.x;
  const float* x = seq + (long)b*NTOK*EMB;
  float v0 = x[tid], v1 = x[tid+256];
  __shared__ float red[256];
  red[tid]=v0+v1; __syncthreads();
  for(int s=128;s>0;s>>=1){ if(tid<s) red[tid]+=red[tid+s]; __syncthreads(); }
  float mu = red[0]*(1.0f/512.0f); __syncthreads();
  float d0=v0-mu, d1=v1-mu;
  red[tid]=d0*d0+d1*d1; __syncthreads();
  for(int s=128;s>0;s>>=1){ if(tid<s) red[tid]+=red[tid+s]; __syncthreads(); }
  float rstd = rsqrtf(red[0]*(1.0f/512.0f) + 1e-5f);
  out[b*512+tid]     = d0*rstd*g[tid]     + bb[tid];
  out[b*512+tid+256] = d1*rstd*g[tid+256] + bb[tid+256];
}

// ---------------- host ----------------
static inline void gemm(hipStream_t st, int TB, int SPLIT,
  const float* A,const float* B,float* C,
  int M,int N,int K,int lda,int ldb,int ldc,
  long sAb,long sAh,long sBb,long sBh,long sCb,long sCh,int nh,int nb,
  float alpha,const float* bias,int relu,int mode,int rowoff,float diagc){
  dim3 g(N/64, M/64, nb);
  if(!TB && !SPLIT)      k_mf<0,0><<<g,256,0,st>>>(A,B,C,K,lda,ldb,ldc,sAb,sAh,sBb,sBh,sCb,sCh,nh,alpha,bias,relu,mode,rowoff,diagc);
  else if(TB && !SPLIT)  k_mf<1,0><<<g,256,0,st>>>(A,B,C,K,lda,ldb,ldc,sAb,sAh,sBb,sBh,sCb,sCh,nh,alpha,bias,relu,mode,rowoff,diagc);
  else if(!TB && SPLIT)  k_mf<0,1><<<g,256,0,st>>>(A,B,C,K,lda,ldb,ldc,sAb,sAh,sBb,sBh,sCb,sCh,nh,alpha,bias,relu,mode,rowoff,diagc);
  else                   k_mf<1,1><<<g,256,0,st>>>(A,B,C,K,lda,ldb,ldc,sAb,sAh,sBb,sBh,sCb,sCh,nh,alpha,bias,relu,mode,rowoff,diagc);
}

extern "C" void kernel_launch(void* const* d_in, const int* in_sizes, int n_in,
                              void* d_out, int out_size, void* d_ws, size_t ws_size,
                              hipStream_t stream) {
  const float* in[24];
  for(int i=0;i<24;i++) in[i] = (const float*)d_in[i];

  float* W = (float*)d_ws;
  size_t off = 0;
  float* seqA = W+off; off += 2L*NTOK*EMB;
  float* seqB = W+off; off += 2L*NTOK*EMB;
  float* xp   = W+off; off += 2L*NP*EMB;
  float* qkvb = W+off; off += 2L*NP*1536;
  float* q_l  = W+off; off += 2L*HEADS*LM*DH;
  float* k_l  = W+off; off += 2L*HEADS*LM*DH;
  float* att2 = W+off; off += 16L*65536;
  float* Z0   = W+off; off += 16L*65536;
  float* Z1   = W+off; off += 16L*65536;
  float* XZ   = W+off; off += 16L*65536;
  float* Tm   = W+off; off += 16L*65536;
  float* Um   = W+off; off += 16L*65536;
  float* avb  = W+off; off += 16L*LM*DH;
  float* zav  = W+off; off += 16L*LM*DH;
  float* bigA = W+off; off += 16L*(long)LM*NP;
  float* Qc   = W+off; off += 2L*NP*EMB;
  float* rmax = W+off; off += 16;
  float* cmax = W+off; off += 16;
  if (ws_size < off*sizeof(float)) return;

  // fc1: relu(h @ w_fc1 + b) into seqA tokens 1..4096
  gemm(stream,0,0, in[0], in[1], seqA+EMB, 4096,512,1024, 1024,512,512,
      4096L*1024,0, 0,0, (long)NTOK*EMB,0, 1,2, 1.0f, in[2], 1, 0, 0, 0.f);
  k_cls<<<2,512,0,stream>>>(in[3], seqA);

  auto attention = [&](float* seq, const float* lng,const float* lnb,
                       const float* qkvw,const float* outw,const float* outb,const float* resk){
    k_ln_pad<<<dim3(NP,2),256,0,stream>>>(seq, xp, lng, lnb);
    gemm(stream,0,0, xp, qkvw, qkvb, NP,1536,512, 512,1536,1536,
        (long)NP*512,0, 0,0, (long)NP*1536,0, 1,2, 1.0f,nullptr,0,0,0, 0.f);
    k_landmarks<<<dim3(LM,HEADS,2),64,0,stream>>>(qkvb, q_l, k_l);
    // attn2 = softmax(q_l @ k_l^T)
    gemm(stream,1,0, q_l, k_l, att2, LM,LM,DH, DH,DH,LM,
        16384,0, 16384,0, 65536,0, 1,16, 1.0f,nullptr,0,0,0, 0.f);
    k_softmax<<<16*LM,256,0,stream>>>(att2, LM, LM);
    // pinv(attn2) -> Z0 (split-bf16 for precision)
    k_pinv_norm<<<16,256,0,stream>>>(att2, rmax, cmax);
    k_pinv_zinit<<<dim3(LM,16),256,0,stream>>>(att2, Z0, rmax, cmax);
    for(int it=0; it<6; it++){
      float* zin  = (it&1)?Z1:Z0;
      float* zout = (it&1)?Z0:Z1;
      gemm(stream,0,1, att2, zin, XZ, LM,LM,LM, LM,LM,LM, 65536,0,65536,0,65536,0, 1,16, 1.0f,nullptr,0,0,0, 0.f);
      k_isub<<<4096,256,0,stream>>>(XZ, Tm, 7.0f);
      gemm(stream,0,1, XZ, Tm, Um, LM,LM,LM, LM,LM,LM, 65536,0,65536,0,65536,0, 1,16, -1.0f,nullptr,0,0,0, 15.0f);
      gemm(stream,0,1, XZ, Um, Tm, LM,LM,LM, LM,LM,LM, 65536,0,65536,0,65536,0, 1,16, -1.0f,nullptr,0,0,0, 13.0f);
      gemm(stream,0,1, zin, Tm, zout, LM,LM,LM, LM,LM,LM, 65536,0,65536,0,65536,0, 1,16, 0.25f,nullptr,0,0,0, 0.f);
    }
    // attn3 = softmax(q_l @ k^T); av = attn3 @ v
    gemm(stream,1,0, q_l, qkvb+512, bigA, LM,NP,DH, DH,1536,NP,
        8L*16384,16384, (long)NP*1536,64, 8L*LM*NP,(long)LM*NP, 8,16, 1.0f,nullptr,0,0,0, 0.f);
    k_softmax<<<16*LM,256,0,stream>>>(bigA, NP, NP);
    gemm(stream,0,0, bigA, qkvb+1024, avb, LM,DH,NP, NP,1536,DH,
        8L*LM*NP,(long)LM*NP, (long)NP*1536,64, 8L*16384,16384, 8,16, 1.0f,nullptr,0,0,0, 0.f);
    // attn1 = softmax(SCALE * q @ k_l^T)
    gemm(stream,1,0, qkvb, k_l, bigA, NP,LM,DH, 1536,DH,LM,
        (long)NP*1536,64, 8L*16384,16384, 8L*NP*LM,(long)NP*LM, 8,16, SCALE,nullptr,0,0,0, 0.f);
    k_softmax<<<16*NP,256,0,stream>>>(bigA, LM, LM);
    // out = attn1 @ (Z0 @ av)
    gemm(stream,0,0, Z0, avb, zav, LM,DH,LM, LM,DH,DH, 65536,0, 16384,0, 16384,0, 1,16, 1.0f,nullptr,0,0,0, 0.f);
    gemm(stream,0,0, bigA, zav, Qc, NP,DH,LM, LM,DH,EMB,
        8L*NP*LM,(long)NP*LM, 8L*16384,16384, (long)NP*EMB,64, 8,16, 1.0f,nullptr,0,0,0, 0.f);
    k_res_conv<<<dim3(NP,HEADS,2),64,0,stream>>>(qkvb, resk, Qc);
    // out proj + residual add into seq
    gemm(stream,0,0, Qc, outw, seq, NP,EMB,EMB, EMB,EMB,EMB,
        (long)NP*EMB,0, 0,0, (long)NTOK*EMB,0, 1,2, 1.0f, outb, 0, 1, PADF, 0.f);
  };

  attention(seqA, in[4], in[5], in[6], in[7], in[8], in[9]);
  k_ppeg<<<dim3(32,4,2),256,0,stream>>>(seqA, seqB, in[10],in[11],in[12],in[13],in[14],in[15]);
  attention(seqB, in[16], in[17], in[18], in[19], in[20], in[21]);
  k_final_ln<<<2,256,0,stream>>>(seqB, in[22], in[23], (float*)d_out);
}

// Round 5
// 1775.010 us; speedup vs baseline: 3.1293x; 1.4453x over previous
//
#include <hip/hip_runtime.h>
#include <hip/hip_bf16.h>

#define HEADS 8
#define DH 64
#define EMB 512
#define NP 4352
#define NTOK 4097
#define PADF 255
#define LM 256
#define SCALE 0.125f

typedef __attribute__((ext_vector_type(8))) short bf8;
typedef __attribute__((ext_vector_type(4))) float f4;
typedef __attribute__((ext_vector_type(8))) unsigned short us8;
typedef __attribute__((ext_vector_type(4))) unsigned short us4;
typedef unsigned short u16;

__device__ __forceinline__ u16 f2b(float f){
  union { float f; unsigned u; } x; x.f = f;
  unsigned r = x.u + 0x7fffu + ((x.u>>16)&1u);
  return (u16)(r>>16);
}
__device__ __forceinline__ float b2f(u16 h){
  union { unsigned u; float f; } x; x.u = ((unsigned)h)<<16;
  return x.f;
}

// ---------------- bf16 MFMA GEMM (fp32 in/out) ----------------
// mode 0: store; mode 1: C[gm-rowoff] += v (rows<rowoff dropped); mode 3: atomicAdd
// grid.x = nx*ksplit; K divided into ksplit chunks.
template<int TB>
__global__ __launch_bounds__(256)
void k_mf(const float* __restrict__ A, const float* __restrict__ B, float* __restrict__ C,
    int K,int lda,int ldb,int ldc,
    long sAb,long sAh,long sBb,long sBh,long sCb,long sCh,int nh,
    float alpha, const float* __restrict__ bias, int relu, int mode, int rowoff,
    int nx, int ksplit)
{
  int z = blockIdx.z;
  const float* Ab = A + (long)(z/nh)*sAb + (long)(z%nh)*sAh;
  const float* Bb = B + (long)(z/nh)*sBb + (long)(z%nh)*sBh;
  float* Cb = C + (long)(z/nh)*sCb + (long)(z%nh)*sCh;
  int bx = blockIdx.x % nx, kc = blockIdx.x / nx;
  int m0 = blockIdx.y*64, n0 = bx*64;
  int klen = K/ksplit, kbeg = kc*klen, kend = kbeg+klen;
  __shared__ u16 As[64*40];
  __shared__ u16 Bs[64*40];
  int tid = threadIdx.x;
  int w = tid>>6, lane = tid&63, q = lane>>4, lr = lane&15;
  f4 acc[4] = {};
  for(int k0=kbeg;k0<kend;k0+=32){
    #pragma unroll
    for(int p=0;p<2;p++){
      int idx = tid + p*256;
      int m = idx>>3, kcc = (idx&7)*4;
      float4 v = *(const float4*)&Ab[(long)(m0+m)*lda + k0 + kcc];
      int o = m*40 + kcc;
      As[o]=f2b(v.x); As[o+1]=f2b(v.y); As[o+2]=f2b(v.z); As[o+3]=f2b(v.w);
    }
    if(TB){
      #pragma unroll
      for(int p=0;p<2;p++){
        int idx = tid + p*256;
        int n = idx>>3, kcc = (idx&7)*4;
        float4 v = *(const float4*)&Bb[(long)(n0+n)*ldb + k0 + kcc];
        int o = n*40 + kcc;
        Bs[o]=f2b(v.x); Bs[o+1]=f2b(v.y); Bs[o+2]=f2b(v.z); Bs[o+3]=f2b(v.w);
      }
    } else {
      #pragma unroll
      for(int p=0;p<2;p++){
        int idx = tid + p*256;
        int kk = idx>>4, n4 = (idx&15)*4;
        float4 v = *(const float4*)&Bb[(long)(k0+kk)*ldb + n0 + n4];
        Bs[(n4  )*40+kk]=f2b(v.x); Bs[(n4+1)*40+kk]=f2b(v.y);
        Bs[(n4+2)*40+kk]=f2b(v.z); Bs[(n4+3)*40+kk]=f2b(v.w);
      }
    }
    __syncthreads();
    bf8 af = *(const bf8*)&As[(w*16+lr)*40 + q*8];
    #pragma unroll
    for(int t=0;t<4;t++){
      bf8 bf = *(const bf8*)&Bs[(t*16+lr)*40 + q*8];
      acc[t] = __builtin_amdgcn_mfma_f32_16x16x32_bf16(af, bf, acc[t], 0,0,0);
    }
    __syncthreads();
  }
  #pragma unroll
  for(int t=0;t<4;t++){
    #pragma unroll
    for(int r=0;r<4;r++){
      int gm = m0 + w*16 + q*4 + r;
      int gn = n0 + t*16 + lr;
      float v = acc[t][r]*alpha;
      if(bias) v += bias[gn];
      if(relu) v = fmaxf(v,0.f);
      if(mode==0) Cb[(long)gm*ldc+gn] = v;
      else if(mode==3) atomicAdd(&Cb[(long)gm*ldc+gn], v);
      else if(gm>=rowoff) Cb[(long)(gm-rowoff)*ldc+gn] += v;
    }
  }
}

// ---------------- pinv GEMM on bf16 hi/lo pairs ----------------
// S = sum_k Abuf[m][k]*Bbuf[n][k] (both row-contiguous, 256x256, batch z)
// out pair: alpha*S + diag*I
__global__ __launch_bounds__(256)
void k_pg(const u16* __restrict__ Ah, const u16* __restrict__ Al,
          const u16* __restrict__ Bh, const u16* __restrict__ Bl,
          u16* __restrict__ Oh, u16* __restrict__ Ol, float alpha, float diag)
{
  long zo = (long)blockIdx.z*65536;
  int m0 = blockIdx.y*64, n0 = blockIdx.x*64;
  __shared__ u16 Ash[64*40], Asl[64*40], Bsh[64*40], Bsl[64*40];
  int tid = threadIdx.x;
  int w = tid>>6, lane = tid&63, q = lane>>4, lr = lane&15;
  int sm = tid>>2, sk = (tid&3)*8;
  f4 acc[4] = {};
  for(int k0=0;k0<256;k0+=32){
    *(us8*)&Ash[sm*40+sk] = *(const us8*)&Ah[zo+(long)(m0+sm)*256+k0+sk];
    *(us8*)&Asl[sm*40+sk] = *(const us8*)&Al[zo+(long)(m0+sm)*256+k0+sk];
    *(us8*)&Bsh[sm*40+sk] = *(const us8*)&Bh[zo+(long)(n0+sm)*256+k0+sk];
    *(us8*)&Bsl[sm*40+sk] = *(const us8*)&Bl[zo+(long)(n0+sm)*256+k0+sk];
    __syncthreads();
    bf8 ah = *(const bf8*)&Ash[(w*16+lr)*40 + q*8];
    bf8 al = *(const bf8*)&Asl[(w*16+lr)*40 + q*8];
    #pragma unroll
    for(int t=0;t<4;t++){
      bf8 bh = *(const bf8*)&Bsh[(t*16+lr)*40 + q*8];
      bf8 bl = *(const bf8*)&Bsl[(t*16+lr)*40 + q*8];
      acc[t] = __builtin_amdgcn_mfma_f32_16x16x32_bf16(ah, bh, acc[t], 0,0,0);
      acc[t] = __builtin_amdgcn_mfma_f32_16x16x32_bf16(ah, bl, acc[t], 0,0,0);
      acc[t] = __builtin_amdgcn_mfma_f32_16x16x32_bf16(al, bh, acc[t], 0,0,0);
    }
    __syncthreads();
  }
  #pragma unroll
  for(int t=0;t<4;t++){
    #pragma unroll
    for(int r=0;r<4;r++){
      int gm = m0 + w*16 + q*4 + r;
      int gn = n0 + t*16 + lr;
      float v = alpha*acc[t][r] + ((gm==gn)?diag:0.f);
      u16 h = f2b(v);
      long o = zo + (long)gm*256 + gn;
      Oh[o] = h; Ol[o] = f2b(v - b2f(h));
    }
  }
}

// cls token row
__global__ void k_cls(const float* __restrict__ cls, float* __restrict__ seq){
  int b = blockIdx.x;
  seq[(long)b*NTOK*EMB + threadIdx.x] = cls[threadIdx.x];
}

// LayerNorm of seq into xp with 255 zero rows at front
__global__ void k_ln_pad(const float* __restrict__ seq, float* __restrict__ xp,
                         const float* __restrict__ g, const float* __restrict__ bb){
  int b = blockIdx.y, i = blockIdx.x, tid = threadIdx.x;
  float* out = xp + ((long)b*NP + i)*EMB;
  if(i < PADF){ out[tid]=0.0f; out[tid+256]=0.0f; return; }
  const float* x = seq + ((long)b*NTOK + (i-PADF))*EMB;
  float v0 = x[tid], v1 = x[tid+256];
  __shared__ float red[256];
  red[tid]=v0+v1; __syncthreads();
  for(int s=128;s>0;s>>=1){ if(tid<s) red[tid]+=red[tid+s]; __syncthreads(); }
  float mu = red[0]*(1.0f/512.0f); __syncthreads();
  float d0=v0-mu, d1=v1-mu;
  red[tid]=d0*d0+d1*d1; __syncthreads();
  for(int s=128;s>0;s>>=1){ if(tid<s) red[tid]+=red[tid+s]; __syncthreads(); }
  float rstd = rsqrtf(red[0]*(1.0f/512.0f) + 1e-5f);
  out[tid]     = d0*rstd*g[tid]     + bb[tid];
  out[tid+256] = d1*rstd*g[tid+256] + bb[tid+256];
}

__global__ void k_landmarks(const float* __restrict__ qkv, float* __restrict__ q_l, float* __restrict__ k_l){
  int j = blockIdx.x, h = blockIdx.y, b = blockIdx.z, d = threadIdx.x;
  const float* base = qkv + (long)b*NP*1536 + h*64 + d;
  float sq=0.f, sk=0.f;
  for(int l=0;l<17;l++){
    long row = (long)(j*17+l)*1536;
    sq += base[row];
    sk += base[row+512];
  }
  long o = (((long)b*HEADS + h)*LM + j)*DH + d;
  q_l[o] = sq * (SCALE/17.0f);
  k_l[o] = sk * (1.0f/17.0f);
}

__global__ void k_softmax(float* __restrict__ X, int cols, int ld){
  long row = blockIdx.x;
  float* p = X + row*(long)ld;
  int tid = threadIdx.x;
  __shared__ float red[256];
  float mx = -1e30f;
  for(int j=tid;j<cols;j+=256) mx = fmaxf(mx, p[j]);
  red[tid]=mx; __syncthreads();
  for(int s=128;s>0;s>>=1){ if(tid<s) red[tid]=fmaxf(red[tid],red[tid+s]); __syncthreads(); }
  mx = red[0]; __syncthreads();
  float sum=0.f;
  for(int j=tid;j<cols;j+=256){ float e = expf(p[j]-mx); p[j]=e; sum+=e; }
  red[tid]=sum; __syncthreads();
  for(int s=128;s>0;s>>=1){ if(tid<s) red[tid]+=red[tid+s]; __syncthreads(); }
  float inv = 1.0f/red[0];
  for(int j=tid;j<cols;j+=256) p[j] *= inv;
}

__global__ void k_pinv_norm(const float* __restrict__ A2, float* __restrict__ rmax, float* __restrict__ cmax){
  int z = blockIdx.x, tid = threadIdx.x;
  const float* X = A2 + (long)z*65536;
  float rs=0.f, cs=0.f;
  for(int j=0;j<256;j++){ rs += fabsf(X[tid*256+j]); cs += fabsf(X[j*256+tid]); }
  __shared__ float r1[256], r2[256];
  r1[tid]=rs; r2[tid]=cs; __syncthreads();
  for(int s=128;s>0;s>>=1){ if(tid<s){ r1[tid]=fmaxf(r1[tid],r1[tid+s]); r2[tid]=fmaxf(r2[tid],r2[tid+s]); } __syncthreads(); }
  if(tid==0){ rmax[z]=r1[0]; cmax[z]=r2[0]; }
}

// pairs: X = att2; Zt = att2*inv; Z = att2^T*inv  (all bf16 hi/lo)
__global__ void k_pair_init(const float* __restrict__ att2,
    const float* __restrict__ rmax, const float* __restrict__ cmax,
    u16* __restrict__ Xh, u16* __restrict__ Xl,
    u16* __restrict__ Zh, u16* __restrict__ Zl,
    u16* __restrict__ Zth, u16* __restrict__ Ztl)
{
  long zo = (long)blockIdx.z*65536;
  int i0 = blockIdx.y*64, j0 = blockIdx.x*64;
  float rm=0.f, cm=0.f;
  for(int t=0;t<16;t++){ rm=fmaxf(rm,rmax[t]); cm=fmaxf(cm,cmax[t]); }
  float inv = 1.0f/(rm*cm);
  __shared__ float T[64][68];
  int tid = threadIdx.x;
  int li = tid>>2, jc = (tid&3)*16;
  #pragma unroll
  for(int u=0;u<4;u++){
    float4 v = *(const float4*)&att2[zo + (long)(i0+li)*256 + j0 + jc + u*4];
    T[li][jc+u*4]=v.x; T[li][jc+u*4+1]=v.y; T[li][jc+u*4+2]=v.z; T[li][jc+u*4+3]=v.w;
    long o = zo + (long)(i0+li)*256 + j0 + jc + u*4;
    float vv[4] = {v.x,v.y,v.z,v.w};
    us4 xh, xl, zth, ztl;
    #pragma unroll
    for(int c=0;c<4;c++){
      u16 h = f2b(vv[c]); xh[c]=h; xl[c]=f2b(vv[c]-b2f(h));
      float zt = vv[c]*inv;
      u16 h2 = f2b(zt); zth[c]=h2; ztl[c]=f2b(zt-b2f(h2));
    }
    *(us4*)&Xh[o]=xh; *(us4*)&Xl[o]=xl; *(us4*)&Zth[o]=zth; *(us4*)&Ztl[o]=ztl;
  }
  __syncthreads();
  int lj = tid>>2, ic = (tid&3)*16;
  #pragma unroll
  for(int r=0;r<16;r++){
    float x = T[ic+r][lj]*inv;
    u16 h = f2b(x);
    long o = zo + (long)(j0+lj)*256 + i0 + ic + r;
    Zh[o]=h; Zl[o]=f2b(x-b2f(h));
  }
}

__global__ void k_pair2f(const u16* __restrict__ H, const u16* __restrict__ L, float* __restrict__ O, long n){
  long i = (long)blockIdx.x*256 + threadIdx.x;
  if(i<n) O[i] = b2f(H[i]) + b2f(L[i]);
}

__global__ void k_zero(float* __restrict__ p, long n){
  long i = (long)blockIdx.x*256 + threadIdx.x;
  if(i<n) p[i] = 0.f;
}

// res conv: tiled. block = (64-token tile, head, batch); LDS v tile 96x64
__global__ __launch_bounds__(256)
void k_rconv(const float* __restrict__ qkv, const float* __restrict__ resk, float* __restrict__ Q){
  int t0 = blockIdx.x*64, h = blockIdx.y, b = blockIdx.z;
  __shared__ float V[96*64];
  const float* vb = qkv + (long)b*NP*1536 + 1024 + h*64;
  int tid = threadIdx.x;
  #pragma unroll
  for(int s=0;s<6;s++){
    int idx = tid + s*256;
    int row = idx>>4, c4 = (idx&15)*4;
    int p = t0 - 16 + row;
    float4 v = {0,0,0,0};
    if(p>=0 && p<NP) v = *(const float4*)&vb[(long)p*1536 + c4];
    *(float4*)&V[row*64+c4] = v;
  }
  __syncthreads();
  int d = tid&63, lt = (tid>>6)*16;
  float acc[16] = {};
  #pragma unroll
  for(int s=0;s<48;s++){
    float val = V[(lt+s)*64 + d];
    #pragma unroll
    for(int j=0;j<16;j++){
      int tap = s - j;
      if(tap>=0 && tap<33) acc[j] += resk[h*33+tap]*val;
    }
  }
  #pragma unroll
  for(int j=0;j<16;j++){
    int i = t0 + lt + j;
    Q[((long)b*NP + i)*EMB + h*64 + d] += acc[j];
  }
}

// PPEG: weights in LDS; block = 128 ch x 2 rows
__global__ __launch_bounds__(256)
void k_ppeg(const float* __restrict__ seq, float* __restrict__ out,
    const float* __restrict__ w7,const float* __restrict__ b7,
    const float* __restrict__ w5,const float* __restrict__ b5,
    const float* __restrict__ w3,const float* __restrict__ b3){
  int b = blockIdx.z, cg = blockIdx.y, rp = blockIdx.x;
  int ch0 = cg*128;
  __shared__ float s7[128*49], s5[128*25], s3[128*9], sbias[128];
  int tid = threadIdx.x;
  for(int i=tid;i<128*49;i+=256) s7[i] = w7[ch0*49+i];
  for(int i=tid;i<128*25;i+=256) s5[i] = w5[ch0*25+i];
  for(int i=tid;i<128*9;i+=256)  s3[i] = w3[ch0*9+i];
  if(tid<128) sbias[tid] = b7[ch0+tid]+b5[ch0+tid]+b3[ch0+tid];
  if(cg==0 && rp==0){
    out[(long)b*NTOK*EMB + tid]       = seq[(long)b*NTOK*EMB + tid];
    out[(long)b*NTOK*EMB + 256 + tid] = seq[(long)b*NTOK*EMB + 256 + tid];
  }
  __syncthreads();
  int c = tid & 127;
  int y = rp*2 + (tid>>7);
  const float* sbase = seq + (long)b*NTOK*EMB + EMB + (ch0 + c);
  float* obase = out + (long)b*NTOK*EMB + EMB + (ch0 + c);
  const float* W7 = &s7[c*49];
  const float* W5 = &s5[c*25];
  const float* W3 = &s3[c*9];
  float bsum = sbias[c];
  for(int xc=0;xc<8;xc++){
    int xb = xc*8;
    float acc[8];
    #pragma unroll
    for(int j=0;j<8;j++) acc[j] = sbase[(long)(y*64+xb+j)*EMB] + bsum;
    #pragma unroll
    for(int dy=-3;dy<=3;dy++){
      int yy = y+dy;
      if(yy<0||yy>=64) continue;
      float v[14];
      #pragma unroll
      for(int u=0;u<14;u++){
        int xx = xb + u - 3;
        v[u] = (xx>=0 && xx<64) ? sbase[(long)(yy*64+xx)*EMB] : 0.f;
      }
      #pragma unroll
      for(int dx=-3;dx<=3;dx++){
        float wsum = W7[(dy+3)*7+(dx+3)];
        if(dy>=-2&&dy<=2&&dx>=-2&&dx<=2) wsum += W5[(dy+2)*5+(dx+2)];
        if(dy>=-1&&dy<=1&&dx>=-1&&dx<=1) wsum += W3[(dy+1)*3+(dx+1)];
        #pragma unroll
        for(int j=0;j<8;j++) acc[j] += v[j+dx+3]*wsum;
      }
    }
    #pragma unroll
    for(int j=0;j<8;j++) obase[(long)(y*64+xb+j)*EMB] = acc[j];
  }
}

__global__ void k_final_ln(const float* __restrict__ seq, const float* __restrict__ g,
                           const float* __restrict__ bb, float* __restrict__ out){
  int b = blockIdx.x, tid = threadIdx.x;
  const float* x = seq + (long)b*NTOK*EMB;
  float v0 = x[tid], v1 = x[tid+256];
  __shared__ float red[256];
  red[tid]=v0+v1; __syncthreads();
  for(int s=128;s>0;s>>=1){ if(tid<s) red[tid]+=red[tid+s]; __syncthreads(); }
  float mu = red[0]*(1.0f/512.0f); __syncthreads();
  float d0=v0-mu, d1=v1-mu;
  red[tid]=d0*d0+d1*d1; __syncthreads();
  for(int s=128;s>0;s>>=1){ if(tid<s) red[tid]+=red[tid+s]; __syncthreads(); }
  float rstd = rsqrtf(red[0]*(1.0f/512.0f) + 1e-5f);
  out[b*512+tid]     = d0*rstd*g[tid]     + bb[tid];
  out[b*512+tid+256] = d1*rstd*g[tid+256] + bb[tid+256];
}

// ---------------- host ----------------
static inline void gemm(hipStream_t st, int TB,
  const float* A,const float* B,float* C,
  int M,int N,int K,int lda,int ldb,int ldc,
  long sAb,long sAh,long sBb,long sBh,long sCb,long sCh,int nh,int nb,
  float alpha,const float* bias,int relu,int mode,int rowoff,int ksplit=1){
  int nx = N/64;
  dim3 g(nx*ksplit, M/64, nb);
  if(TB) k_mf<1><<<g,256,0,st>>>(A,B,C,K,lda,ldb,ldc,sAb,sAh,sBb,sBh,sCb,sCh,nh,alpha,bias,relu,mode,rowoff,nx,ksplit);
  else   k_mf<0><<<g,256,0,st>>>(A,B,C,K,lda,ldb,ldc,sAb,sAh,sBb,sBh,sCb,sCh,nh,alpha,bias,relu,mode,rowoff,nx,ksplit);
}

extern "C" void kernel_launch(void* const* d_in, const int* in_sizes, int n_in,
                              void* d_out, int out_size, void* d_ws, size_t ws_size,
                              hipStream_t stream) {
  const float* in[24];
  for(int i=0;i<24;i++) in[i] = (const float*)d_in[i];

  float* W = (float*)d_ws;
  size_t off = 0;
  float* seqA = W+off; off += 2L*NTOK*EMB;
  float* seqB = W+off; off += 2L*NTOK*EMB;
  float* xp   = W+off; off += 2L*NP*EMB;
  float* qkvb = W+off; off += 2L*NP*1536;
  float* q_l  = W+off; off += 2L*HEADS*LM*DH;
  float* k_l  = W+off; off += 2L*HEADS*LM*DH;
  float* att2 = W+off; off += 16L*65536;
  float* Zf   = W+off; off += 16L*65536;
  float* avb  = W+off; off += 16L*LM*DH;
  float* zav  = W+off; off += 16L*LM*DH;
  float* bigA = W+off; off += 16L*(long)LM*NP;   // pinv pairs aliased here
  float* Qc   = W+off; off += 2L*NP*EMB;
  float* rmax = W+off; off += 16;
  float* cmax = W+off; off += 16;
  if (ws_size < off*sizeof(float)) return;

  // bf16 pair buffers aliased into bigA (dead during pinv): 18 x 1MB-in-floats/2
  const long PB = 16L*65536;          // elements per pair buffer (u16)
  u16* pair = (u16*)bigA;             // 18 * PB u16 = 36 MB < bigA's 71 MB
  u16 *Xh = pair,        *Xl = pair+PB;
  u16 *Z0h = pair+2*PB,  *Z0l = pair+3*PB,  *Z0th = pair+4*PB,  *Z0tl = pair+5*PB;
  u16 *Z1h = pair+6*PB,  *Z1l = pair+7*PB,  *Z1th = pair+8*PB,  *Z1tl = pair+9*PB;
  u16 *Ph = pair+10*PB,  *Pl = pair+11*PB;
  u16 *Tth = pair+12*PB, *Ttl = pair+13*PB;
  u16 *Uth = pair+14*PB, *Utl = pair+15*PB;
  u16 *Vth = pair+16*PB, *Vtl = pair+17*PB;

  // fc1: relu(h @ w_fc1 + b) into seqA tokens 1..4096
  gemm(stream,0, in[0], in[1], seqA+EMB, 4096,512,1024, 1024,512,512,
      4096L*1024,0, 0,0, (long)NTOK*EMB,0, 1,2, 1.0f, in[2], 1, 0, 0);
  k_cls<<<2,512,0,stream>>>(in[3], seqA);

  auto attention = [&](float* seq, const float* lng,const float* lnb,
                       const float* qkvw,const float* outw,const float* outb,const float* resk){
    k_ln_pad<<<dim3(NP,2),256,0,stream>>>(seq, xp, lng, lnb);
    gemm(stream,0, xp, qkvw, qkvb, NP,1536,512, 512,1536,1536,
        (long)NP*512,0, 0,0, (long)NP*1536,0, 1,2, 1.0f,nullptr,0,0,0);
    k_landmarks<<<dim3(LM,HEADS,2),64,0,stream>>>(qkvb, q_l, k_l);
    // attn2 = softmax(q_l @ k_l^T)
    gemm(stream,1, q_l, k_l, att2, LM,LM,DH, DH,DH,LM,
        16384,0, 16384,0, 65536,0, 1,16, 1.0f,nullptr,0,0,0);
    k_softmax<<<16*LM,256,0,stream>>>(att2, LM, LM);
    // pinv on bf16 pairs
    k_pinv_norm<<<16,256,0,stream>>>(att2, rmax, cmax);
    k_pair_init<<<dim3(4,4,16),256,0,stream>>>(att2, rmax, cmax, Xh,Xl, Z0h,Z0l, Z0th,Z0tl);
    dim3 pgrid(4,4,16);
    for(int it=0; it<6; it++){
      u16 *Zh_=(it&1)?Z1h:Z0h, *Zl_=(it&1)?Z1l:Z0l, *Zth_=(it&1)?Z1th:Z0th, *Ztl_=(it&1)?Z1tl:Z0tl;
      u16 *Nh_=(it&1)?Z0h:Z1h, *Nl_=(it&1)?Z0l:Z1l, *Nth_=(it&1)?Z0th:Z1th, *Ntl_=(it&1)?Z0tl:Z1tl;
      k_pg<<<pgrid,256,0,stream>>>(Xh,Xl,   Zth_,Ztl_, Ph,Pl,   1.0f, 0.f);   // P = X@Z
      k_pg<<<pgrid,256,0,stream>>>(Zth_,Ztl_, Xh,Xl,   Tth,Ttl, -1.0f, 7.f);  // Tt = 7I - P^T
      k_pg<<<pgrid,256,0,stream>>>(Tth,Ttl, Ph,Pl,     Uth,Utl, -1.0f, 15.f); // Ut = 15I - (P@T)^T
      k_pg<<<pgrid,256,0,stream>>>(Uth,Utl, Ph,Pl,     Vth,Vtl, -1.0f, 13.f); // Vt = 13I - (P@U)^T
      k_pg<<<pgrid,256,0,stream>>>(Zh_,Zl_, Vth,Vtl,   Nh_,Nl_, 0.25f, 0.f);  // Znew = 0.25 Z@V
      if(it<5)
        k_pg<<<pgrid,256,0,stream>>>(Vth,Vtl, Zh_,Zl_, Nth_,Ntl_, 0.25f, 0.f); // Znew^T
    }
    k_pair2f<<<4096,256,0,stream>>>(Z0h, Z0l, Zf, PB);
    // attn3 = softmax(q_l @ k^T); av = attn3 @ v (split-K atomic)
    gemm(stream,1, q_l, qkvb+512, bigA, LM,NP,DH, DH,1536,NP,
        8L*16384,16384, (long)NP*1536,64, 8L*LM*NP,(long)LM*NP, 8,16, 1.0f,nullptr,0,0,0);
    k_softmax<<<16*LM,256,0,stream>>>(bigA, NP, NP);
    k_zero<<<2048,256,0,stream>>>(avb, 2L*16*LM*DH);   // avb + zav
    gemm(stream,0, bigA, qkvb+1024, avb, LM,DH,NP, NP,1536,DH,
        8L*LM*NP,(long)LM*NP, (long)NP*1536,64, 8L*16384,16384, 8,16, 1.0f,nullptr,0,3,0, 17);
    // attn1 = softmax(SCALE * q @ k_l^T)
    gemm(stream,1, qkvb, k_l, bigA, NP,LM,DH, 1536,DH,LM,
        (long)NP*1536,64, 8L*16384,16384, 8L*NP*LM,(long)NP*LM, 8,16, SCALE,nullptr,0,0,0);
    k_softmax<<<16*NP,256,0,stream>>>(bigA, LM, LM);
    // zav = Z @ avb (split-K atomic), out = attn1 @ zav
    gemm(stream,0, Zf, avb, zav, LM,DH,LM, LM,DH,DH, 65536,0, 16384,0, 16384,0, 1,16,
        1.0f,nullptr,0,3,0, 4);
    gemm(stream,0, bigA, zav, Qc, NP,DH,LM, LM,DH,EMB,
        8L*NP*LM,(long)NP*LM, 8L*16384,16384, (long)NP*EMB,64, 8,16, 1.0f,nullptr,0,0,0);
    k_rconv<<<dim3(NP/64,HEADS,2),256,0,stream>>>(qkvb, resk, Qc);
    // out proj + residual add into seq
    gemm(stream,0, Qc, outw, seq, NP,EMB,EMB, EMB,EMB,EMB,
        (long)NP*EMB,0, 0,0, (long)NTOK*EMB,0, 1,2, 1.0f, outb, 0, 1, PADF);
  };

  attention(seqA, in[4], in[5], in[6], in[7], in[8], in[9]);
  k_ppeg<<<dim3(32,4,2),256,0,stream>>>(seqA, seqB, in[10],in[11],in[12],in[13],in[14],in[15]);
  attention(seqB, in[16], in[17], in[18], in[19], in[20], in[21]);
  k_final_ln<<<2,256,0,stream>>>(seqB, in[22], in[23], (float*)d_out);
}

// Round 7
// 1491.229 us; speedup vs baseline: 3.7249x; 1.1903x over previous
//
#include <hip/hip_runtime.h>
#include <hip/hip_bf16.h>

#define HEADS 8
#define DH 64
#define EMB 512
#define NP 4352
#define NTOK 4097
#define PADF 255
#define LM 256
#define SCALE 0.125f

typedef __attribute__((ext_vector_type(8))) short bf8;
typedef __attribute__((ext_vector_type(4))) float f4;
typedef __attribute__((ext_vector_type(8))) unsigned short us8;
typedef __attribute__((ext_vector_type(4))) unsigned short us4;
typedef unsigned short u16;

__device__ __forceinline__ u16 f2b(float f){
  union { float f; unsigned u; } x; x.f = f;
  unsigned r = x.u + 0x7fffu + ((x.u>>16)&1u);
  return (u16)(r>>16);
}
__device__ __forceinline__ float b2f(u16 h){
  union { unsigned u; float f; } x; x.u = ((unsigned)h)<<16;
  return x.f;
}

__device__ __forceinline__ void gload_lds(const u16* g, u16* l){
  __builtin_amdgcn_global_load_lds((const __attribute__((address_space(1))) void*)g,
                                   (__attribute__((address_space(3))) void*)l, 16, 0, 0);
}

// ======== 128x128 NT bf16 GEMM, BK=32, global_load_lds staging ========
// C[m][n] = alpha * sum_k A[m][k]*B[n][k]  (+bias[n]) (+relu)
// MODE 0: fp32 store; MODE 2: bf16 store; MODE 3: fp32 C[gm-rowoff] += v (gm<rowoff dropped)
template<int MODE>
__global__ __launch_bounds__(256)
void k_g128(const u16* __restrict__ A, const u16* __restrict__ B,
            float* __restrict__ C, u16* __restrict__ C16,
            int K, int lda, int ldb, int ldc,
            long sAb, long sAh, long sBb, long sBh, long sCb, long sCh, int nh,
            float alpha, const float* __restrict__ bias, int relu, int rowoff)
{
  int z = blockIdx.z;
  const u16* Ab = A + (long)(z/nh)*sAb + (long)(z%nh)*sAh;
  const u16* Bb = B + (long)(z/nh)*sBb + (long)(z%nh)*sBh;
  long cb = (long)(z/nh)*sCb + (long)(z%nh)*sCh;
  int m0 = blockIdx.y*128, n0 = blockIdx.x*128;
  __shared__ u16 As[128*32];
  __shared__ u16 Bs[128*32];
  int tid=threadIdx.x, w=tid>>6, lane=tid&63, q=lane>>4, lr=lane&15;
  int wrow=(w>>1)*64, wcol=(w&1)*64;
  int srow = tid>>2, scol = (tid&3)*8;
  const u16* ga  = Ab + (long)(m0+srow)*lda + scol;
  const u16* ga2 = Ab + (long)(m0+64+srow)*lda + scol;
  const u16* gb  = Bb + (long)(n0+srow)*ldb + scol;
  const u16* gb2 = Bb + (long)(n0+64+srow)*ldb + scol;
  u16* la  = &As[srow*32 + scol];
  u16* la2 = &As[(64+srow)*32 + scol];
  u16* lb  = &Bs[srow*32 + scol];
  u16* lb2 = &Bs[(64+srow)*32 + scol];
  f4 acc[4][4] = {};
  for(int k0=0;k0<K;k0+=32){
    gload_lds(ga, la);  gload_lds(ga2, la2);
    gload_lds(gb, lb);  gload_lds(gb2, lb2);
    ga+=32; ga2+=32; gb+=32; gb2+=32;
    __syncthreads();
    bf8 af[4], bfr[4];
    #pragma unroll
    for(int r=0;r<4;r++) af[r]  = *(const bf8*)&As[(wrow + r*16 + lr)*32 + q*8];
    #pragma unroll
    for(int t=0;t<4;t++) bfr[t] = *(const bf8*)&Bs[(wcol + t*16 + lr)*32 + q*8];
    #pragma unroll
    for(int r=0;r<4;r++)
      #pragma unroll
      for(int t=0;t<4;t++)
        acc[r][t] = __builtin_amdgcn_mfma_f32_16x16x32_bf16(af[r], bfr[t], acc[r][t], 0,0,0);
    __syncthreads();
  }
  #pragma unroll
  for(int r=0;r<4;r++){
    #pragma unroll
    for(int t=0;t<4;t++){
      #pragma unroll
      for(int e=0;e<4;e++){
        int gm = m0 + wrow + r*16 + q*4 + e;
        int gn = n0 + wcol + t*16 + lr;
        float v = acc[r][t][e]*alpha;
        if(bias) v += bias[gn];
        if(relu) v = fmaxf(v,0.f);
        if(MODE==0) C[cb + (long)gm*ldc + gn] = v;
        else if(MODE==2) C16[cb + (long)gm*ldc + gn] = f2b(v);
        else { if(gm>=rowoff) C[cb + (long)(gm-rowoff)*ldc + gn] += v; }
      }
    }
  }
}

// ======== 64x64 NT bf16 GEMM, split-K capable ========
// MODE 0: fp32 store; MODE 2: bf16 store; MODE 3: fp32 atomicAdd
template<int MODE>
__global__ __launch_bounds__(256)
void k_g64(const u16* __restrict__ A, const u16* __restrict__ B,
           float* __restrict__ C, u16* __restrict__ C16,
           int K, int lda, int ldb, int ldc,
           long sAb, long sAh, long sBb, long sBh, long sCb, long sCh, int nh,
           float alpha, int nx, int ksplit)
{
  int z = blockIdx.z;
  const u16* Ab = A + (long)(z/nh)*sAb + (long)(z%nh)*sAh;
  const u16* Bb = B + (long)(z/nh)*sBb + (long)(z%nh)*sBh;
  long cb = (long)(z/nh)*sCb + (long)(z%nh)*sCh;
  int bx = blockIdx.x % nx, kc = blockIdx.x / nx;
  int m0 = blockIdx.y*64, n0 = bx*64;
  int klen = K/ksplit, kbeg = kc*klen;
  __shared__ u16 As[64*32];
  __shared__ u16 Bs[64*32];
  int tid=threadIdx.x, w=tid>>6, lane=tid&63, q=lane>>4, lr=lane&15;
  int srow = tid>>2, scol = (tid&3)*8;
  const u16* ga = Ab + (long)(m0+srow)*lda + kbeg + scol;
  const u16* gb = Bb + (long)(n0+srow)*ldb + kbeg + scol;
  u16* la = &As[srow*32 + scol];
  u16* lb = &Bs[srow*32 + scol];
  f4 acc[4] = {};
  for(int kk=0;kk<klen;kk+=32){
    gload_lds(ga, la); gload_lds(gb, lb);
    ga+=32; gb+=32;
    __syncthreads();
    bf8 af = *(const bf8*)&As[(w*16 + lr)*32 + q*8];
    #pragma unroll
    for(int t=0;t<4;t++){
      bf8 bfr = *(const bf8*)&Bs[(t*16 + lr)*32 + q*8];
      acc[t] = __builtin_amdgcn_mfma_f32_16x16x32_bf16(af, bfr, acc[t], 0,0,0);
    }
    __syncthreads();
  }
  #pragma unroll
  for(int t=0;t<4;t++){
    #pragma unroll
    for(int e=0;e<4;e++){
      int gm = m0 + w*16 + q*4 + e;
      int gn = n0 + t*16 + lr;
      float v = acc[t][e]*alpha;
      if(MODE==0) C[cb + (long)gm*ldc + gn] = v;
      else if(MODE==2) C16[cb + (long)gm*ldc + gn] = f2b(v);
      else atomicAdd(&C[cb + (long)gm*ldc + gn], v);
    }
  }
}

// ======== pinv GEMM on bf16 hi/lo pairs ========
__global__ __launch_bounds__(256)
void k_pg(const u16* __restrict__ Ah, const u16* __restrict__ Al,
          const u16* __restrict__ Bh, const u16* __restrict__ Bl,
          u16* __restrict__ Oh, u16* __restrict__ Ol, float alpha, float diag)
{
  long zo = (long)blockIdx.z*65536;
  int m0 = blockIdx.y*64, n0 = blockIdx.x*64;
  __shared__ u16 Ash[64*40], Asl[64*40], Bsh[64*40], Bsl[64*40];
  int tid = threadIdx.x;
  int w = tid>>6, lane = tid&63, q = lane>>4, lr = lane&15;
  int sm = tid>>2, sk = (tid&3)*8;
  f4 acc[4] = {};
  for(int k0=0;k0<256;k0+=32){
    *(us8*)&Ash[sm*40+sk] = *(const us8*)&Ah[zo+(long)(m0+sm)*256+k0+sk];
    *(us8*)&Asl[sm*40+sk] = *(const us8*)&Al[zo+(long)(m0+sm)*256+k0+sk];
    *(us8*)&Bsh[sm*40+sk] = *(const us8*)&Bh[zo+(long)(n0+sm)*256+k0+sk];
    *(us8*)&Bsl[sm*40+sk] = *(const us8*)&Bl[zo+(long)(n0+sm)*256+k0+sk];
    __syncthreads();
    bf8 ah = *(const bf8*)&Ash[(w*16+lr)*40 + q*8];
    bf8 al = *(const bf8*)&Asl[(w*16+lr)*40 + q*8];
    #pragma unroll
    for(int t=0;t<4;t++){
      bf8 bh = *(const bf8*)&Bsh[(t*16+lr)*40 + q*8];
      bf8 bl = *(const bf8*)&Bsl[(t*16+lr)*40 + q*8];
      acc[t] = __builtin_amdgcn_mfma_f32_16x16x32_bf16(ah, bh, acc[t], 0,0,0);
      acc[t] = __builtin_amdgcn_mfma_f32_16x16x32_bf16(ah, bl, acc[t], 0,0,0);
      acc[t] = __builtin_amdgcn_mfma_f32_16x16x32_bf16(al, bh, acc[t], 0,0,0);
    }
    __syncthreads();
  }
  #pragma unroll
  for(int t=0;t<4;t++){
    #pragma unroll
    for(int r=0;r<4;r++){
      int gm = m0 + w*16 + q*4 + r;
      int gn = n0 + t*16 + lr;
      float v = alpha*acc[t][r] + ((gm==gn)?diag:0.f);
      u16 h = f2b(v);
      long o = zo + (long)gm*256 + gn;
      Oh[o] = h; Ol[o] = f2b(v - b2f(h));
    }
  }
}

// pair transpose: OH[j][i]=H[i][j], OL likewise (per z)
__global__ __launch_bounds__(256)
void k_ptrans(const u16* __restrict__ H, const u16* __restrict__ L,
              u16* __restrict__ OH, u16* __restrict__ OL){
  long zo = (long)blockIdx.z*65536;
  int i0 = blockIdx.y*64, j0 = blockIdx.x*64;
  __shared__ u16 TH[64][72], TL[64][72];
  int tid=threadIdx.x;
  for(int s=0;s<2;s++){
    int idx=tid+s*256; int row=idx>>3, c8=(idx&7)*8;
    *(us8*)&TH[row][c8] = *(const us8*)&H[zo + (long)(i0+row)*256 + j0 + c8];
    *(us8*)&TL[row][c8] = *(const us8*)&L[zo + (long)(i0+row)*256 + j0 + c8];
  }
  __syncthreads();
  int d = tid>>2, c0=(tid&3)*16;
  us8 h0,h1,l0,l1;
  #pragma unroll
  for(int jj=0;jj<8;jj++){
    h0[jj]=TH[c0+jj][d]; h1[jj]=TH[c0+8+jj][d];
    l0[jj]=TL[c0+jj][d]; l1[jj]=TL[c0+8+jj][d];
  }
  long ob = zo + (long)(j0+d)*256 + i0;
  *(us8*)&OH[ob + c0] = h0; *(us8*)&OH[ob + c0 + 8] = h1;
  *(us8*)&OL[ob + c0] = l0; *(us8*)&OL[ob + c0 + 8] = l1;
}

// weight transpose+convert: in fp32 [K][N] -> out bf16 [N][K]
__global__ void k_wT(const float* __restrict__ in, u16* __restrict__ out, int K, int N){
  int n0=blockIdx.x*32, k0=blockIdx.y*32, tid=threadIdx.x;
  __shared__ float T[32][33];
  int lr=tid&31, lc=tid>>5;
  #pragma unroll
  for(int p=0;p<4;p++) T[lc+8*p][lr] = in[(long)(k0+lc+8*p)*N + n0+lr];
  __syncthreads();
  #pragma unroll
  for(int p=0;p<4;p++) out[(long)(n0+lc+8*p)*K + k0+lr] = f2b(T[lr][lc+8*p]);
}

// v^T: qkvb16 v-section [NP][64] per (b,h) -> vT [b][h][64][NP]
__global__ __launch_bounds__(256)
void k_vT(const u16* __restrict__ qkv16, u16* __restrict__ vT){
  int t0=blockIdx.x*64, h=blockIdx.y, b=blockIdx.z, tid=threadIdx.x;
  __shared__ u16 T[64][72];
  const u16* src = qkv16 + (long)b*NP*1536 + 1024 + h*64;
  for(int s=0;s<2;s++){
    int idx=tid+s*256; int row=idx>>3, c8=(idx&7)*8;
    *(us8*)&T[row][c8] = *(const us8*)&src[(long)(t0+row)*1536 + c8];
  }
  __syncthreads();
  u16* dst = vT + ((long)(b*8+h)*64)*NP;
  int d = tid>>2, j0=(tid&3)*16;
  us8 v0,v1;
  #pragma unroll
  for(int jj=0;jj<8;jj++){ v0[jj]=T[j0+jj][d]; v1[jj]=T[j0+8+jj][d]; }
  *(us8*)&dst[(long)d*NP + t0 + j0]     = v0;
  *(us8*)&dst[(long)d*NP + t0 + j0 + 8] = v1;
}

__global__ void k_cvt16(const float* __restrict__ in, u16* __restrict__ out, long n){
  long i = (long)blockIdx.x*256 + threadIdx.x;
  if(i<n) out[i] = f2b(in[i]);
}

__global__ void k_zero(float* __restrict__ p, long n){
  long i = (long)blockIdx.x*256 + threadIdx.x;
  if(i<n) p[i] = 0.f;
}

__global__ void k_cls(const float* __restrict__ cls, float* __restrict__ seq){
  int b = blockIdx.x;
  seq[(long)b*NTOK*EMB + threadIdx.x] = cls[threadIdx.x];
}

// LayerNorm of seq into xpb bf16 with 255 zero rows at front
__global__ void k_ln_pad(const float* __restrict__ seq, u16* __restrict__ xp,
                         const float* __restrict__ g, const float* __restrict__ bb){
  int b = blockIdx.y, i = blockIdx.x, tid = threadIdx.x;
  u16* out = xp + ((long)b*NP + i)*EMB;
  if(i < PADF){ out[tid]=0; out[tid+256]=0; return; }
  const float* x = seq + ((long)b*NTOK + (i-PADF))*EMB;
  float v0 = x[tid], v1 = x[tid+256];
  __shared__ float red[256];
  red[tid]=v0+v1; __syncthreads();
  for(int s=128;s>0;s>>=1){ if(tid<s) red[tid]+=red[tid+s]; __syncthreads(); }
  float mu = red[0]*(1.0f/512.0f); __syncthreads();
  float d0=v0-mu, d1=v1-mu;
  red[tid]=d0*d0+d1*d1; __syncthreads();
  for(int s=128;s>0;s>>=1){ if(tid<s) red[tid]+=red[tid+s]; __syncthreads(); }
  float rstd = rsqrtf(red[0]*(1.0f/512.0f) + 1e-5f);
  out[tid]     = f2b(d0*rstd*g[tid]     + bb[tid]);
  out[tid+256] = f2b(d1*rstd*g[tid+256] + bb[tid+256]);
}

__global__ void k_landmarks(const u16* __restrict__ qkv, u16* __restrict__ q_l, u16* __restrict__ k_l){
  int j = blockIdx.x, h = blockIdx.y, b = blockIdx.z, d = threadIdx.x;
  const u16* base = qkv + (long)b*NP*1536 + h*64 + d;
  float sq=0.f, sk=0.f;
  for(int l=0;l<17;l++){
    long row = (long)(j*17+l)*1536;
    sq += b2f(base[row]);
    sk += b2f(base[row+512]);
  }
  long o = (((long)b*HEADS + h)*LM + j)*DH + d;
  q_l[o] = f2b(sq * (SCALE/17.0f));
  k_l[o] = f2b(sk * (1.0f/17.0f));
}

// fp32 in-place row softmax
__global__ void k_softmax(float* __restrict__ X, int cols){
  float* p = X + (long)blockIdx.x*cols;
  int tid = threadIdx.x;
  __shared__ float red[256];
  float mx = -1e30f;
  for(int j=tid;j<cols;j+=256) mx = fmaxf(mx, p[j]);
  red[tid]=mx; __syncthreads();
  for(int s=128;s>0;s>>=1){ if(tid<s) red[tid]=fmaxf(red[tid],red[tid+s]); __syncthreads(); }
  mx = red[0]; __syncthreads();
  float sum=0.f;
  for(int j=tid;j<cols;j+=256){ float e = expf(p[j]-mx); p[j]=e; sum+=e; }
  red[tid]=sum; __syncthreads();
  for(int s=128;s>0;s>>=1){ if(tid<s) red[tid]+=red[tid+s]; __syncthreads(); }
  float inv = 1.0f/red[0];
  for(int j=tid;j<cols;j+=256) p[j] *= inv;
}

// bf16 in-place row softmax (row cached in LDS)
__global__ void k_softmax16(u16* __restrict__ X, int cols){
  __shared__ u16 buf[4352];
  __shared__ float red[256];
  u16* p = X + (long)blockIdx.x*cols;
  int tid = threadIdx.x;
  for(int j=tid;j<cols;j+=256) buf[j]=p[j];
  __syncthreads();
  float mx = -1e30f;
  for(int j=tid;j<cols;j+=256) mx = fmaxf(mx, b2f(buf[j]));
  red[tid]=mx; __syncthreads();
  for(int s=128;s>0;s>>=1){ if(tid<s) red[tid]=fmaxf(red[tid],red[tid+s]); __syncthreads(); }
  mx = red[0]; __syncthreads();
  float sum=0.f;
  for(int j=tid;j<cols;j+=256) sum += expf(b2f(buf[j])-mx);
  red[tid]=sum; __syncthreads();
  for(int s=128;s>0;s>>=1){ if(tid<s) red[tid]+=red[tid+s]; __syncthreads(); }
  float inv = 1.0f/red[0];
  for(int j=tid;j<cols;j+=256) p[j] = f2b(expf(b2f(buf[j])-mx)*inv);
}

__global__ void k_pinv_norm(const float* __restrict__ A2, float* __restrict__ rmax, float* __restrict__ cmax){
  int z = blockIdx.x, tid = threadIdx.x;
  const float* X = A2 + (long)z*65536;
  float rs=0.f, cs=0.f;
  for(int j=0;j<256;j++){ rs += fabsf(X[tid*256+j]); cs += fabsf(X[j*256+tid]); }
  __shared__ float r1[256], r2[256];
  r1[tid]=rs; r2[tid]=cs; __syncthreads();
  for(int s=128;s>0;s>>=1){ if(tid<s){ r1[tid]=fmaxf(r1[tid],r1[tid+s]); r2[tid]=fmaxf(r2[tid],r2[tid+s]); } __syncthreads(); }
  if(tid==0){ rmax[z]=r1[0]; cmax[z]=r2[0]; }
}

__global__ void k_pair_init(const float* __restrict__ att2,
    const float* __restrict__ rmax, const float* __restrict__ cmax,
    u16* __restrict__ Xh, u16* __restrict__ Xl,
    u16* __restrict__ Zh, u16* __restrict__ Zl,
    u16* __restrict__ Zth, u16* __restrict__ Ztl)
{
  long zo = (long)blockIdx.z*65536;
  int i0 = blockIdx.y*64, j0 = blockIdx.x*64;
  float rm=0.f, cm=0.f;
  for(int t=0;t<16;t++){ rm=fmaxf(rm,rmax[t]); cm=fmaxf(cm,cmax[t]); }
  float inv = 1.0f/(rm*cm);
  __shared__ float T[64][68];
  int tid = threadIdx.x;
  int li = tid>>2, jc = (tid&3)*16;
  #pragma unroll
  for(int u=0;u<4;u++){
    float4 v = *(const float4*)&att2[zo + (long)(i0+li)*256 + j0 + jc + u*4];
    T[li][jc+u*4]=v.x; T[li][jc+u*4+1]=v.y; T[li][jc+u*4+2]=v.z; T[li][jc+u*4+3]=v.w;
    long o = zo + (long)(i0+li)*256 + j0 + jc + u*4;
    float vv[4] = {v.x,v.y,v.z,v.w};
    us4 xh, xl, zth, ztl;
    #pragma unroll
    for(int c=0;c<4;c++){
      u16 h = f2b(vv[c]); xh[c]=h; xl[c]=f2b(vv[c]-b2f(h));
      float zt = vv[c]*inv;
      u16 h2 = f2b(zt); zth[c]=h2; ztl[c]=f2b(zt-b2f(h2));
    }
    *(us4*)&Xh[o]=xh; *(us4*)&Xl[o]=xl; *(us4*)&Zth[o]=zth; *(us4*)&Ztl[o]=ztl;
  }
  __syncthreads();
  int lj = tid>>2, ic = (tid&3)*16;
  #pragma unroll
  for(int r=0;r<16;r++){
    float x = T[ic+r][lj]*inv;
    u16 h = f2b(x);
    long o = zo + (long)(j0+lj)*256 + i0 + ic + r;
    Zh[o]=h; Zl[o]=f2b(x-b2f(h));
  }
}

// res conv: bf16 v staged to LDS fp32
__global__ __launch_bounds__(256)
void k_rconv(const u16* __restrict__ qkv16, const float* __restrict__ resk, float* __restrict__ Q){
  int t0 = blockIdx.x*64, h = blockIdx.y, b = blockIdx.z;
  __shared__ float V[96*64];
  const u16* vb = qkv16 + (long)b*NP*1536 + 1024 + h*64;
  int tid = threadIdx.x;
  #pragma unroll
  for(int s=0;s<3;s++){
    int idx = tid + s*256;
    int row = idx>>3, c8 = (idx&7)*8;
    int p = t0 - 16 + row;
    if(p>=0 && p<NP){
      us8 v = *(const us8*)&vb[(long)p*1536 + c8];
      #pragma unroll
      for(int jj=0;jj<8;jj++) V[row*64+c8+jj] = b2f(v[jj]);
    } else {
      #pragma unroll
      for(int jj=0;jj<8;jj++) V[row*64+c8+jj] = 0.f;
    }
  }
  __syncthreads();
  int d = tid&63, lt = (tid>>6)*16;
  float acc[16] = {};
  #pragma unroll
  for(int s=0;s<48;s++){
    float val = V[(lt+s)*64 + d];
    #pragma unroll
    for(int j=0;j<16;j++){
      int tap = s - j;
      if(tap>=0 && tap<33) acc[j] += resk[h*33+tap]*val;
    }
  }
  #pragma unroll
  for(int j=0;j<16;j++){
    int i = t0 + lt + j;
    Q[((long)b*NP + i)*EMB + h*64 + d] += acc[j];
  }
}

// PPEG (fp32, unchanged)
__global__ __launch_bounds__(256)
void k_ppeg(const float* __restrict__ seq, float* __restrict__ out,
    const float* __restrict__ w7,const float* __restrict__ b7,
    const float* __restrict__ w5,const float* __restrict__ b5,
    const float* __restrict__ w3,const float* __restrict__ b3){
  int b = blockIdx.z, cg = blockIdx.y, rp = blockIdx.x;
  int ch0 = cg*128;
  __shared__ float s7[128*49], s5[128*25], s3[128*9], sbias[128];
  int tid = threadIdx.x;
  for(int i=tid;i<128*49;i+=256) s7[i] = w7[ch0*49+i];
  for(int i=tid;i<128*25;i+=256) s5[i] = w5[ch0*25+i];
  for(int i=tid;i<128*9;i+=256)  s3[i] = w3[ch0*9+i];
  if(tid<128) sbias[tid] = b7[ch0+tid]+b5[ch0+tid]+b3[ch0+tid];
  if(cg==0 && rp==0){
    out[(long)b*NTOK*EMB + tid]       = seq[(long)b*NTOK*EMB + tid];
    out[(long)b*NTOK*EMB + 256 + tid] = seq[(long)b*NTOK*EMB + 256 + tid];
  }
  __syncthreads();
  int c = tid & 127;
  int y = rp*2 + (tid>>7);
  const float* sbase = seq + (long)b*NTOK*EMB + EMB + (ch0 + c);
  float* obase = out + (long)b*NTOK*EMB + EMB + (ch0 + c);
  const float* W7 = &s7[c*49];
  const float* W5 = &s5[c*25];
  const float* W3 = &s3[c*9];
  float bsum = sbias[c];
  for(int xc=0;xc<8;xc++){
    int xb = xc*8;
    float acc[8];
    #pragma unroll
    for(int j=0;j<8;j++) acc[j] = sbase[(long)(y*64+xb+j)*EMB] + bsum;
    #pragma unroll
    for(int dy=-3;dy<=3;dy++){
      int yy = y+dy;
      if(yy<0||yy>=64) continue;
      float v[14];
      #pragma unroll
      for(int u=0;u<14;u++){
        int xx = xb + u - 3;
        v[u] = (xx>=0 && xx<64) ? sbase[(long)(yy*64+xx)*EMB] : 0.f;
      }
      #pragma unroll
      for(int dx=-3;dx<=3;dx++){
        float wsum = W7[(dy+3)*7+(dx+3)];
        if(dy>=-2&&dy<=2&&dx>=-2&&dx<=2) wsum += W5[(dy+2)*5+(dx+2)];
        if(dy>=-1&&dy<=1&&dx>=-1&&dx<=1) wsum += W3[(dy+1)*3+(dx+1)];
        #pragma unroll
        for(int j=0;j<8;j++) acc[j] += v[j+dx+3]*wsum;
      }
    }
    #pragma unroll
    for(int j=0;j<8;j++) obase[(long)(y*64+xb+j)*EMB] = acc[j];
  }
}

__global__ void k_final_ln(const float* __restrict__ seq, const float* __restrict__ g,
                           const float* __restrict__ bb, float* __restrict__ out){
  int b = blockIdx.x, tid = threadIdx.x;
  const float* x = seq + (long)b*NTOK*EMB;
  float v0 = x[tid], v1 = x[tid+256];
  __shared__ float red[256];
  red[tid]=v0+v1; __syncthreads();
  for(int s=128;s>0;s>>=1){ if(tid<s) red[tid]+=red[tid+s]; __syncthreads(); }
  float mu = red[0]*(1.0f/512.0f); __syncthreads();
  float d0=v0-mu, d1=v1-mu;
  red[tid]=d0*d0+d1*d1; __syncthreads();
  for(int s=128;s>0;s>>=1){ if(tid<s) red[tid]+=red[tid+s]; __syncthreads(); }
  float rstd = rsqrtf(red[0]*(1.0f/512.0f) + 1e-5f);
  out[b*512+tid]     = d0*rstd*g[tid]     + bb[tid];
  out[b*512+tid+256] = d1*rstd*g[tid+256] + bb[tid+256];
}

// ---------------- host ----------------
extern "C" void kernel_launch(void* const* d_in, const int* in_sizes, int n_in,
                              void* d_out, int out_size, void* d_ws, size_t ws_size,
                              hipStream_t stream) {
  const float* in[24];
  for(int i=0;i<24;i++) in[i] = (const float*)d_in[i];

  float* W = (float*)d_ws;
  size_t off = 0;
  float* seqA = W+off; off += 4195328;        // 2*4097*512
  float* seqB = W+off; off += 4195328;
  float* att2 = W+off; off += 1048576;        // 16*65536
  float* Qc   = W+off; off += 4456448;        // 2*4352*512
  float* avbT = W+off; off += 262144;         // 16*64*256
  u16* xpb    = (u16*)(W+off); off += 2228224;  // 2*4352*512 u16
  u16* qkvb16 = (u16*)(W+off); off += 6684672;  // 2*4352*1536 u16
  u16* vT16   = (u16*)(W+off); off += 2228224;
  u16* q_l16  = (u16*)(W+off); off += 131072;   // 16*256*64 u16
  u16* k_l16  = (u16*)(W+off); off += 131072;
  u16* sc16   = (u16*)(W+off); off += 8912896;  // 16*256*4352 u16
  u16* avbT16 = (u16*)(W+off); off += 131072;
  u16* zavT16 = (u16*)(W+off); off += 131072;
  u16* Qc16   = (u16*)(W+off); off += 2228224;
  u16* qkvwT1 = (u16*)(W+off); off += 393216;   // 1536*512 u16
  u16* qkvwT2 = (u16*)(W+off); off += 393216;
  u16* outwT1 = (u16*)(W+off); off += 131072;   // 512*512 u16
  u16* outwT2 = (u16*)(W+off); off += 131072;
  u16* pairs  = (u16*)(W+off); off += 9437184;  // 18*16*65536 u16
  float* rmax = W+off; off += 16;
  float* cmax = W+off; off += 16;
  if (ws_size < off*sizeof(float)) return;

  // h16 + wfc1T aliased inside sc16 (sc16 first written later, in attention())
  u16* h16   = sc16;                  // 8388608 u16
  u16* wfc1T = sc16 + 8388608;        // 524288 u16

  const long PB = 1048576;  // 16*65536
  u16 *Xh=pairs, *Xl=pairs+PB;
  u16 *Z0h=pairs+2*PB, *Z0l=pairs+3*PB, *Z0th=pairs+4*PB, *Z0tl=pairs+5*PB;
  u16 *Z1h=pairs+6*PB, *Z1l=pairs+7*PB, *Z1th=pairs+8*PB, *Z1tl=pairs+9*PB;
  u16 *Ph=pairs+10*PB, *Pl=pairs+11*PB;
  u16 *Tth=pairs+12*PB, *Ttl=pairs+13*PB;
  u16 *Uth=pairs+14*PB, *Utl=pairs+15*PB;
  u16 *Vth=pairs+16*PB, *Vtl=pairs+17*PB;

  // weight conversions/transposes
  k_cvt16<<<32768,256,0,stream>>>(in[0], h16, 8388608L);
  k_wT<<<dim3(16,32),256,0,stream>>>(in[1],  wfc1T, 1024, 512);
  k_wT<<<dim3(48,16),256,0,stream>>>(in[6],  qkvwT1, 512, 1536);
  k_wT<<<dim3(48,16),256,0,stream>>>(in[18], qkvwT2, 512, 1536);
  k_wT<<<dim3(16,16),256,0,stream>>>(in[7],  outwT1, 512, 512);
  k_wT<<<dim3(16,16),256,0,stream>>>(in[19], outwT2, 512, 512);

  // fc1 + cls
  k_g128<0><<<dim3(4,32,2),256,0,stream>>>(h16, wfc1T, seqA+EMB, nullptr,
      1024, 1024,1024,512, 4194304L,0, 0,0, (long)NTOK*EMB,0, 1, 1.0f, in[2], 1, 0);
  k_cls<<<2,512,0,stream>>>(in[3], seqA);

  auto attention = [&](float* seq, const float* lng,const float* lnb,
                       const u16* qkvwT, const u16* outwT, const float* outb, const float* resk){
    k_ln_pad<<<dim3(NP,2),256,0,stream>>>(seq, xpb, lng, lnb);
    k_g128<2><<<dim3(12,34,2),256,0,stream>>>(xpb, qkvwT, nullptr, qkvb16,
        512, 512,512,1536, (long)NP*512,0, 0,0, (long)NP*1536,0, 1, 1.0f, nullptr, 0, 0);
    k_landmarks<<<dim3(LM,HEADS,2),64,0,stream>>>(qkvb16, q_l16, k_l16);
    k_vT<<<dim3(68,8,2),256,0,stream>>>(qkvb16, vT16);
    // attn2 = softmax(q_l @ k_l^T)  (fp32 scores for pinv)
    k_g128<0><<<dim3(2,2,16),256,0,stream>>>(q_l16, k_l16, att2, nullptr,
        64, 64,64,256, 0,16384, 0,16384, 0,65536, 16, 1.0f, nullptr, 0, 0);
    k_softmax<<<4096,256,0,stream>>>(att2, 256);
    // pinv on bf16 pairs
    k_pinv_norm<<<16,256,0,stream>>>(att2, rmax, cmax);
    k_pair_init<<<dim3(4,4,16),256,0,stream>>>(att2, rmax, cmax, Xh,Xl, Z0h,Z0l, Z0th,Z0tl);
    dim3 pgrid(4,4,16);
    for(int it=0; it<6; it++){
      u16 *Zh_=(it&1)?Z1h:Z0h, *Zl_=(it&1)?Z1l:Z0l, *Zth_=(it&1)?Z1th:Z0th, *Ztl_=(it&1)?Z1tl:Z0tl;
      u16 *Nh_=(it&1)?Z0h:Z1h, *Nl_=(it&1)?Z0l:Z1l, *Nth_=(it&1)?Z0th:Z1th, *Ntl_=(it&1)?Z0tl:Z1tl;
      k_pg<<<pgrid,256,0,stream>>>(Xh,Xl,     Zth_,Ztl_, Ph,Pl,   1.0f, 0.f);
      k_pg<<<pgrid,256,0,stream>>>(Zth_,Ztl_, Xh,Xl,     Tth,Ttl, -1.0f, 7.f);
      k_pg<<<pgrid,256,0,stream>>>(Tth,Ttl,   Ph,Pl,     Uth,Utl, -1.0f, 15.f);
      k_pg<<<pgrid,256,0,stream>>>(Uth,Utl,   Ph,Pl,     Vth,Vtl, -1.0f, 13.f);
      k_pg<<<pgrid,256,0,stream>>>(Zh_,Zl_,   Vth,Vtl,   Nh_,Nl_, 0.25f, 0.f);
      if(it<5) k_ptrans<<<pgrid,256,0,stream>>>(Nh_,Nl_, Nth_,Ntl_);
    }
    // attn3 scores = q_l @ k^T -> sc16 (bf16)
    k_g128<2><<<dim3(34,2,16),256,0,stream>>>(q_l16, qkvb16+512, nullptr, sc16,
        64, 64,1536,4352, 131072L,16384, (long)NP*1536,64, 8L*LM*NP,(long)LM*NP, 8, 1.0f, nullptr, 0, 0);
    k_softmax16<<<4096,256,0,stream>>>(sc16, 4352);
    // avbT = v^T @ attn3_sm^T (split-K atomic)
    k_zero<<<1024,256,0,stream>>>(avbT, 262144L);
    k_g64<3><<<dim3(4*17,1,16),256,0,stream>>>(vT16, sc16, avbT, nullptr,
        4352, 4352,4352,256, 2228224L,278528L, 8L*LM*NP,(long)LM*NP, 131072L,16384L, 8, 1.0f, 4, 17);
    k_cvt16<<<1024,256,0,stream>>>(avbT, avbT16, 262144L);
    // zavT = avbT @ Z^T  -> bf16
    k_g64<2><<<dim3(4,1,16),256,0,stream>>>(avbT16, Z0h, nullptr, zavT16,
        256, 256,256,256, 0,16384L, 0,65536L, 0,16384L, 16, 1.0f, 4, 1);
    // attn1 scores = SCALE * q @ k_l^T -> sc16
    k_g128<2><<<dim3(2,34,16),256,0,stream>>>(qkvb16, k_l16, nullptr, sc16,
        64, 1536,64,256, (long)NP*1536,64, 131072L,16384L, 8L*NP*LM,(long)NP*LM, 8, SCALE, nullptr, 0, 0);
    k_softmax16<<<69632,256,0,stream>>>(sc16, 256);
    // Qc = attn1_sm @ zav   (per-head 64-col blocks)
    k_g64<0><<<dim3(1,68,16),256,0,stream>>>(sc16, zavT16, Qc, nullptr,
        256, 256,256,512, 8L*NP*LM,(long)NP*LM, 131072L,16384L, (long)NP*512,64, 8, 1.0f, 1, 1);
    k_rconv<<<dim3(68,8,2),256,0,stream>>>(qkvb16, resk, Qc);
    k_cvt16<<<17408,256,0,stream>>>(Qc, Qc16, 4456448L);
    // out proj + residual add into seq
    k_g128<3><<<dim3(4,34,2),256,0,stream>>>(Qc16, outwT, seq, nullptr,
        512, 512,512,512, (long)NP*512,0, 0,0, (long)NTOK*EMB,0, 1, 1.0f, outb, 0, PADF);
  };

  attention(seqA, in[4], in[5], qkvwT1, outwT1, in[8], in[9]);
  k_ppeg<<<dim3(32,4,2),256,0,stream>>>(seqA, seqB, in[10],in[11],in[12],in[13],in[14],in[15]);
  attention(seqB, in[16], in[17], qkvwT2, outwT2, in[20], in[21]);
  k_final_ln<<<2,256,0,stream>>>(seqB, in[22], in[23], (float*)d_out);
}

// Round 8
// 1190.059 us; speedup vs baseline: 4.6675x; 1.2531x over previous
//
#include <hip/hip_runtime.h>
#include <hip/hip_bf16.h>

#define HEADS 8
#define DH 64
#define EMB 512
#define NP 4352
#define NTOK 4097
#define PADF 255
#define LM 256
#define SCALE 0.125f

typedef __attribute__((ext_vector_type(8))) short bf8;
typedef __attribute__((ext_vector_type(4))) float f4;
typedef __attribute__((ext_vector_type(8))) unsigned short us8;
typedef __attribute__((ext_vector_type(4))) unsigned short us4;
typedef unsigned short u16;

__device__ __forceinline__ u16 f2b(float f){
  union { float f; unsigned u; } x; x.f = f;
  unsigned r = x.u + 0x7fffu + ((x.u>>16)&1u);
  return (u16)(r>>16);
}
__device__ __forceinline__ float b2f(u16 h){
  union { unsigned u; float f; } x; x.u = ((unsigned)h)<<16;
  return x.f;
}

__device__ __forceinline__ void gload_lds(const u16* g, u16* l){
  __builtin_amdgcn_global_load_lds((const __attribute__((address_space(1))) void*)g,
                                   (__attribute__((address_space(3))) void*)l, 16, 0, 0);
}

// ======== 128x128 NT bf16 GEMM, BK=32, global_load_lds staging ========
// MODE 0: fp32 store; MODE 2: bf16 store; MODE 3: fp32 C[gm-rowoff] += v (gm<rowoff dropped)
template<int MODE>
__global__ __launch_bounds__(256)
void k_g128(const u16* __restrict__ A, const u16* __restrict__ B,
            float* __restrict__ C, u16* __restrict__ C16,
            int K, int lda, int ldb, int ldc,
            long sAb, long sAh, long sBb, long sBh, long sCb, long sCh, int nh,
            float alpha, const float* __restrict__ bias, int relu, int rowoff)
{
  int z = blockIdx.z;
  const u16* Ab = A + (long)(z/nh)*sAb + (long)(z%nh)*sAh;
  const u16* Bb = B + (long)(z/nh)*sBb + (long)(z%nh)*sBh;
  long cb = (long)(z/nh)*sCb + (long)(z%nh)*sCh;
  int m0 = blockIdx.y*128, n0 = blockIdx.x*128;
  __shared__ u16 As[128*32];
  __shared__ u16 Bs[128*32];
  int tid=threadIdx.x, w=tid>>6, lane=tid&63, q=lane>>4, lr=lane&15;
  int wrow=(w>>1)*64, wcol=(w&1)*64;
  int srow = tid>>2, scol = (tid&3)*8;
  const u16* ga  = Ab + (long)(m0+srow)*lda + scol;
  const u16* ga2 = Ab + (long)(m0+64+srow)*lda + scol;
  const u16* gb  = Bb + (long)(n0+srow)*ldb + scol;
  const u16* gb2 = Bb + (long)(n0+64+srow)*ldb + scol;
  u16* la  = &As[srow*32 + scol];
  u16* la2 = &As[(64+srow)*32 + scol];
  u16* lb  = &Bs[srow*32 + scol];
  u16* lb2 = &Bs[(64+srow)*32 + scol];
  f4 acc[4][4] = {};
  for(int k0=0;k0<K;k0+=32){
    gload_lds(ga, la);  gload_lds(ga2, la2);
    gload_lds(gb, lb);  gload_lds(gb2, lb2);
    ga+=32; ga2+=32; gb+=32; gb2+=32;
    __syncthreads();
    bf8 af[4], bfr[4];
    #pragma unroll
    for(int r=0;r<4;r++) af[r]  = *(const bf8*)&As[(wrow + r*16 + lr)*32 + q*8];
    #pragma unroll
    for(int t=0;t<4;t++) bfr[t] = *(const bf8*)&Bs[(wcol + t*16 + lr)*32 + q*8];
    #pragma unroll
    for(int r=0;r<4;r++)
      #pragma unroll
      for(int t=0;t<4;t++)
        acc[r][t] = __builtin_amdgcn_mfma_f32_16x16x32_bf16(af[r], bfr[t], acc[r][t], 0,0,0);
    __syncthreads();
  }
  #pragma unroll
  for(int r=0;r<4;r++){
    #pragma unroll
    for(int t=0;t<4;t++){
      #pragma unroll
      for(int e=0;e<4;e++){
        int gm = m0 + wrow + r*16 + q*4 + e;
        int gn = n0 + wcol + t*16 + lr;
        float v = acc[r][t][e]*alpha;
        if(bias) v += bias[gn];
        if(relu) v = fmaxf(v,0.f);
        if(MODE==0) C[cb + (long)gm*ldc + gn] = v;
        else if(MODE==2) C16[cb + (long)gm*ldc + gn] = f2b(v);
        else { if(gm>=rowoff) C[cb + (long)(gm-rowoff)*ldc + gn] += v; }
      }
    }
  }
}

// ======== 64x64 NT bf16 GEMM, split-K capable ========
template<int MODE>
__global__ __launch_bounds__(256)
void k_g64(const u16* __restrict__ A, const u16* __restrict__ B,
           float* __restrict__ C, u16* __restrict__ C16,
           int K, int lda, int ldb, int ldc,
           long sAb, long sAh, long sBb, long sBh, long sCb, long sCh, int nh,
           float alpha, int nx, int ksplit)
{
  int z = blockIdx.z;
  const u16* Ab = A + (long)(z/nh)*sAb + (long)(z%nh)*sAh;
  const u16* Bb = B + (long)(z/nh)*sBb + (long)(z%nh)*sBh;
  long cb = (long)(z/nh)*sCb + (long)(z%nh)*sCh;
  int bx = blockIdx.x % nx, kc = blockIdx.x / nx;
  int m0 = blockIdx.y*64, n0 = bx*64;
  int klen = K/ksplit, kbeg = kc*klen;
  __shared__ u16 As[64*32];
  __shared__ u16 Bs[64*32];
  int tid=threadIdx.x, w=tid>>6, lane=tid&63, q=lane>>4, lr=lane&15;
  int srow = tid>>2, scol = (tid&3)*8;
  const u16* ga = Ab + (long)(m0+srow)*lda + kbeg + scol;
  const u16* gb = Bb + (long)(n0+srow)*ldb + kbeg + scol;
  u16* la = &As[srow*32 + scol];
  u16* lb = &Bs[srow*32 + scol];
  f4 acc[4] = {};
  for(int kk=0;kk<klen;kk+=32){
    gload_lds(ga, la); gload_lds(gb, lb);
    ga+=32; gb+=32;
    __syncthreads();
    bf8 af = *(const bf8*)&As[(w*16 + lr)*32 + q*8];
    #pragma unroll
    for(int t=0;t<4;t++){
      bf8 bfr = *(const bf8*)&Bs[(t*16 + lr)*32 + q*8];
      acc[t] = __builtin_amdgcn_mfma_f32_16x16x32_bf16(af, bfr, acc[t], 0,0,0);
    }
    __syncthreads();
  }
  #pragma unroll
  for(int t=0;t<4;t++){
    #pragma unroll
    for(int e=0;e<4;e++){
      int gm = m0 + w*16 + q*4 + e;
      int gn = n0 + t*16 + lr;
      float v = acc[t][e]*alpha;
      if(MODE==0) C[cb + (long)gm*ldc + gn] = v;
      else if(MODE==2) C16[cb + (long)gm*ldc + gn] = f2b(v);
      else atomicAdd(&C[cb + (long)gm*ldc + gn], v);
    }
  }
}

// ======== pinv GEMM on bf16 hi/lo pairs, async staging, dual-store epilogue ====
// S[m][n] = sum_k A[m][k]*B[n][k] (3-MFMA split). If Oh: Oh/Ol = na*S + nd*I.
// If TOh: TOh/TOl[gn][gm] = ta*S[gm][gn] + td*I.
__global__ __launch_bounds__(256)
void k_pg2(const u16* __restrict__ Ah, const u16* __restrict__ Al,
           const u16* __restrict__ Bh, const u16* __restrict__ Bl,
           u16* __restrict__ Oh, u16* __restrict__ Ol, float na, float nd,
           u16* __restrict__ TOh, u16* __restrict__ TOl, float ta, float td)
{
  long zo = (long)blockIdx.z*65536;
  int m0 = blockIdx.y*64, n0 = blockIdx.x*64;
  __shared__ u16 Ash[64*32], Asl[64*32], Bsh[64*32], Bsl[64*32];
  int tid=threadIdx.x, w=tid>>6, lane=tid&63, q=lane>>4, lr=lane&15;
  int srow=tid>>2, scol=(tid&3)*8;
  const u16* gah = Ah + zo + (long)(m0+srow)*256 + scol;
  const u16* gal = Al + zo + (long)(m0+srow)*256 + scol;
  const u16* gbh = Bh + zo + (long)(n0+srow)*256 + scol;
  const u16* gbl = Bl + zo + (long)(n0+srow)*256 + scol;
  u16* lah=&Ash[srow*32+scol];
  u16* lal=&Asl[srow*32+scol];
  u16* lbh=&Bsh[srow*32+scol];
  u16* lbl=&Bsl[srow*32+scol];
  f4 acc[4] = {};
  for(int k0=0;k0<256;k0+=32){
    gload_lds(gah,lah); gload_lds(gal,lal); gload_lds(gbh,lbh); gload_lds(gbl,lbl);
    gah+=32; gal+=32; gbh+=32; gbl+=32;
    __syncthreads();
    bf8 ah = *(const bf8*)&Ash[(w*16+lr)*32 + q*8];
    bf8 al = *(const bf8*)&Asl[(w*16+lr)*32 + q*8];
    #pragma unroll
    for(int t=0;t<4;t++){
      bf8 bh = *(const bf8*)&Bsh[(t*16+lr)*32 + q*8];
      bf8 bl = *(const bf8*)&Bsl[(t*16+lr)*32 + q*8];
      acc[t] = __builtin_amdgcn_mfma_f32_16x16x32_bf16(ah, bh, acc[t], 0,0,0);
      acc[t] = __builtin_amdgcn_mfma_f32_16x16x32_bf16(ah, bl, acc[t], 0,0,0);
      acc[t] = __builtin_amdgcn_mfma_f32_16x16x32_bf16(al, bh, acc[t], 0,0,0);
    }
    __syncthreads();
  }
  #pragma unroll
  for(int t=0;t<4;t++){
    int gn = n0 + t*16 + lr;
    if(Oh){
      #pragma unroll
      for(int r=0;r<4;r++){
        int gm = m0 + w*16 + q*4 + r;
        float v = na*acc[t][r] + ((gm==gn)?nd:0.f);
        u16 h = f2b(v);
        long o = zo + (long)gm*256 + gn;
        Oh[o] = h; Ol[o] = f2b(v - b2f(h));
      }
    }
    if(TOh){
      us4 th, tl;
      #pragma unroll
      for(int r=0;r<4;r++){
        int gm = m0 + w*16 + q*4 + r;
        float v = ta*acc[t][r] + ((gm==gn)?td:0.f);
        u16 h = f2b(v);
        th[r] = h; tl[r] = f2b(v - b2f(h));
      }
      long o = zo + (long)gn*256 + (m0 + w*16 + q*4);
      *(us4*)&TOh[o] = th; *(us4*)&TOl[o] = tl;
    }
  }
}

// ======== softmax: wave per row, 256 cols ========
__global__ __launch_bounds__(256)
void k_smw32(float* __restrict__ X){
  long row = (long)blockIdx.x*4 + (threadIdx.x>>6);
  int lane = threadIdx.x & 63;
  float* p = X + row*256;
  float4 v = *(float4*)&p[lane*4];
  float m = fmaxf(fmaxf(v.x,v.y),fmaxf(v.z,v.w));
  for(int s=32;s;s>>=1) m = fmaxf(m, __shfl_xor(m, s));
  float e0=expf(v.x-m), e1=expf(v.y-m), e2=expf(v.z-m), e3=expf(v.w-m);
  float sum = e0+e1+e2+e3;
  for(int s=32;s;s>>=1) sum += __shfl_xor(sum, s);
  float inv = 1.f/sum;
  float4 o = {e0*inv, e1*inv, e2*inv, e3*inv};
  *(float4*)&p[lane*4] = o;
}

__global__ __launch_bounds__(256)
void k_smw16(u16* __restrict__ X){
  long row = (long)blockIdx.x*4 + (threadIdx.x>>6);
  int lane = threadIdx.x & 63;
  u16* p = X + row*256;
  us4 v = *(us4*)&p[lane*4];
  float f0=b2f(v[0]), f1=b2f(v[1]), f2=b2f(v[2]), f3=b2f(v[3]);
  float m = fmaxf(fmaxf(f0,f1),fmaxf(f2,f3));
  for(int s=32;s;s>>=1) m = fmaxf(m, __shfl_xor(m, s));
  float e0=expf(f0-m), e1=expf(f1-m), e2=expf(f2-m), e3=expf(f3-m);
  float sum = e0+e1+e2+e3;
  for(int s=32;s;s>>=1) sum += __shfl_xor(sum, s);
  float inv = 1.f/sum;
  us4 o = {f2b(e0*inv), f2b(e1*inv), f2b(e2*inv), f2b(e3*inv)};
  *(us4*)&p[lane*4] = o;
}

// ======== softmax: block per row, 4352 cols, register-resident ========
__global__ __launch_bounds__(256)
void k_smb16(u16* __restrict__ X){
  u16* p = X + (long)blockIdx.x*4352;
  int tid=threadIdx.x, lane=tid&63, w=tid>>6;
  __shared__ float xw[4], sw[4];
  float e[17];
  float m = -1e30f;
  #pragma unroll
  for(int i=0;i<17;i++){ e[i] = b2f(p[tid + i*256]); m = fmaxf(m, e[i]); }
  for(int s=32;s;s>>=1) m = fmaxf(m, __shfl_xor(m, s));
  if(lane==0) xw[w] = m;
  __syncthreads();
  m = fmaxf(fmaxf(xw[0],xw[1]), fmaxf(xw[2],xw[3]));
  float sum = 0.f;
  #pragma unroll
  for(int i=0;i<17;i++){ e[i] = expf(e[i]-m); sum += e[i]; }
  for(int s=32;s;s>>=1) sum += __shfl_xor(sum, s);
  if(lane==0) sw[w] = sum;
  __syncthreads();
  sum = sw[0]+sw[1]+sw[2]+sw[3];
  float inv = 1.f/sum;
  #pragma unroll
  for(int i=0;i<17;i++) p[tid + i*256] = f2b(e[i]*inv);
}

// weight transpose+convert: in fp32 [K][N] -> out bf16 [N][K]
__global__ void k_wT(const float* __restrict__ in, u16* __restrict__ out, int K, int N){
  int n0=blockIdx.x*32, k0=blockIdx.y*32, tid=threadIdx.x;
  __shared__ float T[32][33];
  int lr=tid&31, lc=tid>>5;
  #pragma unroll
  for(int p=0;p<4;p++) T[lc+8*p][lr] = in[(long)(k0+lc+8*p)*N + n0+lr];
  __syncthreads();
  #pragma unroll
  for(int p=0;p<4;p++) out[(long)(n0+lc+8*p)*K + k0+lr] = f2b(T[lr][lc+8*p]);
}

// v^T: qkvb16 v-section [NP][64] per (b,h) -> vT [b][h][64][NP]
__global__ __launch_bounds__(256)
void k_vT(const u16* __restrict__ qkv16, u16* __restrict__ vT){
  int t0=blockIdx.x*64, h=blockIdx.y, b=blockIdx.z, tid=threadIdx.x;
  __shared__ u16 T[64][72];
  const u16* src = qkv16 + (long)b*NP*1536 + 1024 + h*64;
  for(int s=0;s<2;s++){
    int idx=tid+s*256; int row=idx>>3, c8=(idx&7)*8;
    *(us8*)&T[row][c8] = *(const us8*)&src[(long)(t0+row)*1536 + c8];
  }
  __syncthreads();
  u16* dst = vT + ((long)(b*8+h)*64)*NP;
  int d = tid>>2, j0=(tid&3)*16;
  us8 v0,v1;
  #pragma unroll
  for(int jj=0;jj<8;jj++){ v0[jj]=T[j0+jj][d]; v1[jj]=T[j0+8+jj][d]; }
  *(us8*)&dst[(long)d*NP + t0 + j0]     = v0;
  *(us8*)&dst[(long)d*NP + t0 + j0 + 8] = v1;
}

__global__ void k_cvt16(const float* __restrict__ in, u16* __restrict__ out, long n){
  long i = (long)blockIdx.x*256 + threadIdx.x;
  if(i<n) out[i] = f2b(in[i]);
}

__global__ void k_zero(float* __restrict__ p, long n){
  long i = (long)blockIdx.x*256 + threadIdx.x;
  if(i<n) p[i] = 0.f;
}

__global__ void k_cls(const float* __restrict__ cls, float* __restrict__ seq){
  int b = blockIdx.x;
  seq[(long)b*NTOK*EMB + threadIdx.x] = cls[threadIdx.x];
}

// LayerNorm of seq into xpb bf16 with 255 zero rows at front
__global__ void k_ln_pad(const float* __restrict__ seq, u16* __restrict__ xp,
                         const float* __restrict__ g, const float* __restrict__ bb){
  int b = blockIdx.y, i = blockIdx.x, tid = threadIdx.x;
  u16* out = xp + ((long)b*NP + i)*EMB;
  if(i < PADF){ out[tid]=0; out[tid+256]=0; return; }
  const float* x = seq + ((long)b*NTOK + (i-PADF))*EMB;
  float v0 = x[tid], v1 = x[tid+256];
  __shared__ float red[256];
  red[tid]=v0+v1; __syncthreads();
  for(int s=128;s>0;s>>=1){ if(tid<s) red[tid]+=red[tid+s]; __syncthreads(); }
  float mu = red[0]*(1.0f/512.0f); __syncthreads();
  float d0=v0-mu, d1=v1-mu;
  red[tid]=d0*d0+d1*d1; __syncthreads();
  for(int s=128;s>0;s>>=1){ if(tid<s) red[tid]+=red[tid+s]; __syncthreads(); }
  float rstd = rsqrtf(red[0]*(1.0f/512.0f) + 1e-5f);
  out[tid]     = f2b(d0*rstd*g[tid]     + bb[tid]);
  out[tid+256] = f2b(d1*rstd*g[tid+256] + bb[tid+256]);
}

__global__ void k_landmarks(const u16* __restrict__ qkv, u16* __restrict__ q_l, u16* __restrict__ k_l){
  int j = blockIdx.x, h = blockIdx.y, b = blockIdx.z, d = threadIdx.x;
  const u16* base = qkv + (long)b*NP*1536 + h*64 + d;
  float sq=0.f, sk=0.f;
  for(int l=0;l<17;l++){
    long row = (long)(j*17+l)*1536;
    sq += b2f(base[row]);
    sk += b2f(base[row+512]);
  }
  long o = (((long)b*HEADS + h)*LM + j)*DH + d;
  q_l[o] = f2b(sq * (SCALE/17.0f));
  k_l[o] = f2b(sk * (1.0f/17.0f));
}

__global__ void k_pinv_norm(const float* __restrict__ A2, float* __restrict__ rmax, float* __restrict__ cmax){
  int z = blockIdx.x, tid = threadIdx.x;
  const float* X = A2 + (long)z*65536;
  float rs=0.f, cs=0.f;
  for(int j=0;j<256;j++){ rs += fabsf(X[tid*256+j]); cs += fabsf(X[j*256+tid]); }
  __shared__ float r1[256], r2[256];
  r1[tid]=rs; r2[tid]=cs; __syncthreads();
  for(int s=128;s>0;s>>=1){ if(tid<s){ r1[tid]=fmaxf(r1[tid],r1[tid+s]); r2[tid]=fmaxf(r2[tid],r2[tid+s]); } __syncthreads(); }
  if(tid==0){ rmax[z]=r1[0]; cmax[z]=r2[0]; }
}

__global__ void k_pair_init(const float* __restrict__ att2,
    const float* __restrict__ rmax, const float* __restrict__ cmax,
    u16* __restrict__ Xh, u16* __restrict__ Xl,
    u16* __restrict__ Zh, u16* __restrict__ Zl,
    u16* __restrict__ Zth, u16* __restrict__ Ztl)
{
  long zo = (long)blockIdx.z*65536;
  int i0 = blockIdx.y*64, j0 = blockIdx.x*64;
  float rm=0.f, cm=0.f;
  for(int t=0;t<16;t++){ rm=fmaxf(rm,rmax[t]); cm=fmaxf(cm,cmax[t]); }
  float inv = 1.0f/(rm*cm);
  __shared__ float T[64][68];
  int tid = threadIdx.x;
  int li = tid>>2, jc = (tid&3)*16;
  #pragma unroll
  for(int u=0;u<4;u++){
    float4 v = *(const float4*)&att2[zo + (long)(i0+li)*256 + j0 + jc + u*4];
    T[li][jc+u*4]=v.x; T[li][jc+u*4+1]=v.y; T[li][jc+u*4+2]=v.z; T[li][jc+u*4+3]=v.w;
    long o = zo + (long)(i0+li)*256 + j0 + jc + u*4;
    float vv[4] = {v.x,v.y,v.z,v.w};
    us4 xh, xl, zth, ztl;
    #pragma unroll
    for(int c=0;c<4;c++){
      u16 h = f2b(vv[c]); xh[c]=h; xl[c]=f2b(vv[c]-b2f(h));
      float zt = vv[c]*inv;
      u16 h2 = f2b(zt); zth[c]=h2; ztl[c]=f2b(zt-b2f(h2));
    }
    *(us4*)&Xh[o]=xh; *(us4*)&Xl[o]=xl; *(us4*)&Zth[o]=zth; *(us4*)&Ztl[o]=ztl;
  }
  __syncthreads();
  int lj = tid>>2, ic = (tid&3)*16;
  #pragma unroll
  for(int r=0;r<16;r++){
    float x = T[ic+r][lj]*inv;
    u16 h = f2b(x);
    long o = zo + (long)(j0+lj)*256 + i0 + ic + r;
    Zh[o]=h; Zl[o]=f2b(x-b2f(h));
  }
}

// res conv + fused bf16 convert: Qc16 = bf16(Qc + dwconv(v))
__global__ __launch_bounds__(256)
void k_rconv(const u16* __restrict__ qkv16, const float* __restrict__ resk,
             const float* __restrict__ Qin, u16* __restrict__ Qo16){
  int t0 = blockIdx.x*64, h = blockIdx.y, b = blockIdx.z;
  __shared__ float V[96*64];
  const u16* vb = qkv16 + (long)b*NP*1536 + 1024 + h*64;
  int tid = threadIdx.x;
  #pragma unroll
  for(int s=0;s<3;s++){
    int idx = tid + s*256;
    int row = idx>>3, c8 = (idx&7)*8;
    int p = t0 - 16 + row;
    if(p>=0 && p<NP){
      us8 v = *(const us8*)&vb[(long)p*1536 + c8];
      #pragma unroll
      for(int jj=0;jj<8;jj++) V[row*64+c8+jj] = b2f(v[jj]);
    } else {
      #pragma unroll
      for(int jj=0;jj<8;jj++) V[row*64+c8+jj] = 0.f;
    }
  }
  __syncthreads();
  int d = tid&63, lt = (tid>>6)*16;
  float acc[16] = {};
  #pragma unroll
  for(int s=0;s<48;s++){
    float val = V[(lt+s)*64 + d];
    #pragma unroll
    for(int j=0;j<16;j++){
      int tap = s - j;
      if(tap>=0 && tap<33) acc[j] += resk[h*33+tap]*val;
    }
  }
  #pragma unroll
  for(int j=0;j<16;j++){
    long idx = ((long)b*NP + t0 + lt + j)*EMB + h*64 + d;
    Qo16[idx] = f2b(Qin[idx] + acc[j]);
  }
}

// PPEG (fp32)
__global__ __launch_bounds__(256)
void k_ppeg(const float* __restrict__ seq, float* __restrict__ out,
    const float* __restrict__ w7,const float* __restrict__ b7,
    const float* __restrict__ w5,const float* __restrict__ b5,
    const float* __restrict__ w3,const float* __restrict__ b3){
  int b = blockIdx.z, cg = blockIdx.y, rp = blockIdx.x;
  int ch0 = cg*128;
  __shared__ float s7[128*49], s5[128*25], s3[128*9], sbias[128];
  int tid = threadIdx.x;
  for(int i=tid;i<128*49;i+=256) s7[i] = w7[ch0*49+i];
  for(int i=tid;i<128*25;i+=256) s5[i] = w5[ch0*25+i];
  for(int i=tid;i<128*9;i+=256)  s3[i] = w3[ch0*9+i];
  if(tid<128) sbias[tid] = b7[ch0+tid]+b5[ch0+tid]+b3[ch0+tid];
  if(cg==0 && rp==0){
    out[(long)b*NTOK*EMB + tid]       = seq[(long)b*NTOK*EMB + tid];
    out[(long)b*NTOK*EMB + 256 + tid] = seq[(long)b*NTOK*EMB + 256 + tid];
  }
  __syncthreads();
  int c = tid & 127;
  int y = rp*2 + (tid>>7);
  const float* sbase = seq + (long)b*NTOK*EMB + EMB + (ch0 + c);
  float* obase = out + (long)b*NTOK*EMB + EMB + (ch0 + c);
  const float* W7 = &s7[c*49];
  const float* W5 = &s5[c*25];
  const float* W3 = &s3[c*9];
  float bsum = sbias[c];
  for(int xc=0;xc<8;xc++){
    int xb = xc*8;
    float acc[8];
    #pragma unroll
    for(int j=0;j<8;j++) acc[j] = sbase[(long)(y*64+xb+j)*EMB] + bsum;
    #pragma unroll
    for(int dy=-3;dy<=3;dy++){
      int yy = y+dy;
      if(yy<0||yy>=64) continue;
      float v[14];
      #pragma unroll
      for(int u=0;u<14;u++){
        int xx = xb + u - 3;
        v[u] = (xx>=0 && xx<64) ? sbase[(long)(yy*64+xx)*EMB] : 0.f;
      }
      #pragma unroll
      for(int dx=-3;dx<=3;dx++){
        float wsum = W7[(dy+3)*7+(dx+3)];
        if(dy>=-2&&dy<=2&&dx>=-2&&dx<=2) wsum += W5[(dy+2)*5+(dx+2)];
        if(dy>=-1&&dy<=1&&dx>=-1&&dx<=1) wsum += W3[(dy+1)*3+(dx+1)];
        #pragma unroll
        for(int j=0;j<8;j++) acc[j] += v[j+dx+3]*wsum;
      }
    }
    #pragma unroll
    for(int j=0;j<8;j++) obase[(long)(y*64+xb+j)*EMB] = acc[j];
  }
}

__global__ void k_final_ln(const float* __restrict__ seq, const float* __restrict__ g,
                           const float* __restrict__ bb, float* __restrict__ out){
  int b = blockIdx.x, tid = threadIdx.x;
  const float* x = seq + (long)b*NTOK*EMB;
  float v0 = x[tid], v1 = x[tid+256];
  __shared__ float red[256];
  red[tid]=v0+v1; __syncthreads();
  for(int s=128;s>0;s>>=1){ if(tid<s) red[tid]+=red[tid+s]; __syncthreads(); }
  float mu = red[0]*(1.0f/512.0f); __syncthreads();
  float d0=v0-mu, d1=v1-mu;
  red[tid]=d0*d0+d1*d1; __syncthreads();
  for(int s=128;s>0;s>>=1){ if(tid<s) red[tid]+=red[tid+s]; __syncthreads(); }
  float rstd = rsqrtf(red[0]*(1.0f/512.0f) + 1e-5f);
  out[b*512+tid]     = d0*rstd*g[tid]     + bb[tid];
  out[b*512+tid+256] = d1*rstd*g[tid+256] + bb[tid+256];
}

// ---------------- host ----------------
extern "C" void kernel_launch(void* const* d_in, const int* in_sizes, int n_in,
                              void* d_out, int out_size, void* d_ws, size_t ws_size,
                              hipStream_t stream) {
  const float* in[24];
  for(int i=0;i<24;i++) in[i] = (const float*)d_in[i];

  float* W = (float*)d_ws;
  size_t off = 0;
  float* seqA = W+off; off += 4195328;        // 2*4097*512
  float* seqB = W+off; off += 4195328;
  float* att2 = W+off; off += 1048576;        // 16*65536
  float* Qc   = W+off; off += 4456448;        // 2*4352*512
  float* avbT = W+off; off += 262144;         // 16*64*256
  u16* xpb    = (u16*)(W+off); off += 2228224;  // 2*4352*512 u16
  u16* qkvb16 = (u16*)(W+off); off += 6684672;  // 2*4352*1536 u16
  u16* vT16   = (u16*)(W+off); off += 2228224;
  u16* q_l16  = (u16*)(W+off); off += 131072;   // 16*256*64 u16
  u16* k_l16  = (u16*)(W+off); off += 131072;
  u16* sc16   = (u16*)(W+off); off += 8912896;  // 16*256*4352 u16
  u16* avbT16 = (u16*)(W+off); off += 131072;
  u16* zavT16 = (u16*)(W+off); off += 131072;
  u16* Qc16   = (u16*)(W+off); off += 2228224;
  u16* qkvwT1 = (u16*)(W+off); off += 393216;   // 1536*512 u16
  u16* qkvwT2 = (u16*)(W+off); off += 393216;
  u16* outwT1 = (u16*)(W+off); off += 131072;   // 512*512 u16
  u16* outwT2 = (u16*)(W+off); off += 131072;
  u16* pairs  = (u16*)(W+off); off += 9437184;  // 18*16*65536 u16
  float* rmax = W+off; off += 16;
  float* cmax = W+off; off += 16;
  if (ws_size < off*sizeof(float)) return;

  // h16 + wfc1T aliased inside sc16 (sc16 first written later, in attention())
  u16* h16   = sc16;                  // 8388608 u16
  u16* wfc1T = sc16 + 8388608;        // 524288 u16

  const long PB = 1048576;  // 16*65536
  u16 *Xh=pairs, *Xl=pairs+PB;
  u16 *Z0h=pairs+2*PB, *Z0l=pairs+3*PB, *Z0th=pairs+4*PB, *Z0tl=pairs+5*PB;
  u16 *Z1h=pairs+6*PB, *Z1l=pairs+7*PB, *Z1th=pairs+8*PB, *Z1tl=pairs+9*PB;
  u16 *Ph=pairs+10*PB, *Pl=pairs+11*PB;
  u16 *Tth=pairs+12*PB, *Ttl=pairs+13*PB;
  u16 *Uth=pairs+14*PB, *Utl=pairs+15*PB;
  u16 *Vth=pairs+16*PB, *Vtl=pairs+17*PB;

  // weight conversions/transposes
  k_cvt16<<<32768,256,0,stream>>>(in[0], h16, 8388608L);
  k_wT<<<dim3(16,32),256,0,stream>>>(in[1],  wfc1T, 1024, 512);
  k_wT<<<dim3(48,16),256,0,stream>>>(in[6],  qkvwT1, 512, 1536);
  k_wT<<<dim3(48,16),256,0,stream>>>(in[18], qkvwT2, 512, 1536);
  k_wT<<<dim3(16,16),256,0,stream>>>(in[7],  outwT1, 512, 512);
  k_wT<<<dim3(16,16),256,0,stream>>>(in[19], outwT2, 512, 512);

  // fc1 + cls
  k_g128<0><<<dim3(4,32,2),256,0,stream>>>(h16, wfc1T, seqA+EMB, nullptr,
      1024, 1024,1024,512, 4194304L,0, 0,0, (long)NTOK*EMB,0, 1, 1.0f, in[2], 1, 0);
  k_cls<<<2,512,0,stream>>>(in[3], seqA);

  auto attention = [&](float* seq, const float* lng,const float* lnb,
                       const u16* qkvwT, const u16* outwT, const float* outb, const float* resk){
    k_ln_pad<<<dim3(NP,2),256,0,stream>>>(seq, xpb, lng, lnb);
    k_g128<2><<<dim3(12,34,2),256,0,stream>>>(xpb, qkvwT, nullptr, qkvb16,
        512, 512,512,1536, (long)NP*512,0, 0,0, (long)NP*1536,0, 1, 1.0f, nullptr, 0, 0);
    k_landmarks<<<dim3(LM,HEADS,2),64,0,stream>>>(qkvb16, q_l16, k_l16);
    k_vT<<<dim3(68,8,2),256,0,stream>>>(qkvb16, vT16);
    // attn2 = softmax(q_l @ k_l^T)  (fp32 scores for pinv)
    k_g128<0><<<dim3(2,2,16),256,0,stream>>>(q_l16, k_l16, att2, nullptr,
        64, 64,64,256, 0,16384, 0,16384, 0,65536, 16, 1.0f, nullptr, 0, 0);
    k_smw32<<<1024,256,0,stream>>>(att2);
    // pinv on bf16 pairs
    k_pinv_norm<<<16,256,0,stream>>>(att2, rmax, cmax);
    k_pair_init<<<dim3(4,4,16),256,0,stream>>>(att2, rmax, cmax, Xh,Xl, Z0h,Z0l, Z0th,Z0tl);
    dim3 pgrid(4,4,16);
    for(int it=0; it<6; it++){
      u16 *Zh_=(it&1)?Z1h:Z0h, *Zl_=(it&1)?Z1l:Z0l, *Zth_=(it&1)?Z1th:Z0th, *Ztl_=(it&1)?Z1tl:Z0tl;
      u16 *Nh_=(it&1)?Z0h:Z1h, *Nl_=(it&1)?Z0l:Z1l, *Nth_=(it&1)?Z0th:Z1th, *Ntl_=(it&1)?Z0tl:Z1tl;
      // P = X@Z (normal) ; Tt = (7I - P)^T (transposed)
      k_pg2<<<pgrid,256,0,stream>>>(Xh,Xl, Zth_,Ztl_, Ph,Pl,1.0f,0.f, Tth,Ttl,-1.0f,7.f);
      // Ut = (15I - P@T)^T
      k_pg2<<<pgrid,256,0,stream>>>(Ph,Pl, Tth,Ttl, nullptr,nullptr,0.f,0.f, Uth,Utl,-1.0f,15.f);
      // Vt = (13I - P@U)^T
      k_pg2<<<pgrid,256,0,stream>>>(Ph,Pl, Uth,Utl, nullptr,nullptr,0.f,0.f, Vth,Vtl,-1.0f,13.f);
      // Znew = 0.25 Z@V (normal + transposed)
      k_pg2<<<pgrid,256,0,stream>>>(Zh_,Zl_, Vth,Vtl, Nh_,Nl_,0.25f,0.f, Nth_,Ntl_,0.25f,0.f);
    }
    // attn3 scores = q_l @ k^T -> sc16 (bf16)
    k_g128<2><<<dim3(34,2,16),256,0,stream>>>(q_l16, qkvb16+512, nullptr, sc16,
        64, 64,1536,4352, 131072L,16384, (long)NP*1536,64, 8L*LM*NP,(long)LM*NP, 8, 1.0f, nullptr, 0, 0);
    k_smb16<<<4096,256,0,stream>>>(sc16);
    // avbT = v^T @ attn3_sm^T (split-K atomic)
    k_zero<<<1024,256,0,stream>>>(avbT, 262144L);
    k_g64<3><<<dim3(4*17,1,16),256,0,stream>>>(vT16, sc16, avbT, nullptr,
        4352, 4352,4352,256, 2228224L,278528L, 8L*LM*NP,(long)LM*NP, 131072L,16384L, 8, 1.0f, 4, 17);
    k_cvt16<<<1024,256,0,stream>>>(avbT, avbT16, 262144L);
    // zavT = avbT @ Z^T  -> bf16
    k_g64<2><<<dim3(4,1,16),256,0,stream>>>(avbT16, Z0h, nullptr, zavT16,
        256, 256,256,256, 0,16384L, 0,65536L, 0,16384L, 16, 1.0f, 4, 1);
    // attn1 scores = SCALE * q @ k_l^T -> sc16
    k_g128<2><<<dim3(2,34,16),256,0,stream>>>(qkvb16, k_l16, nullptr, sc16,
        64, 1536,64,256, (long)NP*1536,64, 131072L,16384L, 8L*NP*LM,(long)NP*LM, 8, SCALE, nullptr, 0, 0);
    k_smw16<<<17408,256,0,stream>>>(sc16);
    // Qc = attn1_sm @ zav   (per-head 64-col blocks)
    k_g64<0><<<dim3(1,68,16),256,0,stream>>>(sc16, zavT16, Qc, nullptr,
        256, 256,256,512, 8L*NP*LM,(long)NP*LM, 131072L,16384L, (long)NP*512,64, 8, 1.0f, 1, 1);
    // res conv fused with bf16 convert
    k_rconv<<<dim3(68,8,2),256,0,stream>>>(qkvb16, resk, Qc, Qc16);
    // out proj + residual add into seq
    k_g128<3><<<dim3(4,34,2),256,0,stream>>>(Qc16, outwT, seq, nullptr,
        512, 512,512,512, (long)NP*512,0, 0,0, (long)NTOK*EMB,0, 1, 1.0f, outb, 0, PADF);
  };

  attention(seqA, in[4], in[5], qkvwT1, outwT1, in[8], in[9]);
  k_ppeg<<<dim3(32,4,2),256,0,stream>>>(seqA, seqB, in[10],in[11],in[12],in[13],in[14],in[15]);
  attention(seqB, in[16], in[17], qkvwT2, outwT2, in[20], in[21]);
  k_final_ln<<<2,256,0,stream>>>(seqB, in[22], in[23], (float*)d_out);
}

// Round 9
// 1126.913 us; speedup vs baseline: 4.9291x; 1.0560x over previous
//
#include <hip/hip_runtime.h>
#include <hip/hip_bf16.h>

#define HEADS 8
#define DH 64
#define EMB 512
#define NP 4352
#define NTOK 4097
#define PADF 255
#define LM 256
#define SCALE 0.125f

typedef __attribute__((ext_vector_type(8))) short bf8;
typedef __attribute__((ext_vector_type(4))) float f4;
typedef __attribute__((ext_vector_type(8))) unsigned short us8;
typedef __attribute__((ext_vector_type(4))) unsigned short us4;
typedef unsigned short u16;

__device__ __forceinline__ u16 f2b(float f){
  union { float f; unsigned u; } x; x.f = f;
  unsigned r = x.u + 0x7fffu + ((x.u>>16)&1u);
  return (u16)(r>>16);
}
__device__ __forceinline__ float b2f(u16 h){
  union { unsigned u; float f; } x; x.u = ((unsigned)h)<<16;
  return x.f;
}

__device__ __forceinline__ void gload_lds(const u16* g, u16* l){
  __builtin_amdgcn_global_load_lds((const __attribute__((address_space(1))) void*)g,
                                   (__attribute__((address_space(3))) void*)l, 16, 0, 0);
}

// ======== 128x128 NT bf16 GEMM, BK=32, global_load_lds staging ========
// MODE 0: fp32 store; MODE 2: bf16 store; MODE 3: fp32 C[gm-rowoff] += v (gm<rowoff dropped)
template<int MODE>
__global__ __launch_bounds__(256)
void k_g128(const u16* __restrict__ A, const u16* __restrict__ B,
            float* __restrict__ C, u16* __restrict__ C16,
            int K, int lda, int ldb, int ldc,
            long sAb, long sAh, long sBb, long sBh, long sCb, long sCh, int nh,
            float alpha, const float* __restrict__ bias, int relu, int rowoff)
{
  int z = blockIdx.z;
  const u16* Ab = A + (long)(z/nh)*sAb + (long)(z%nh)*sAh;
  const u16* Bb = B + (long)(z/nh)*sBb + (long)(z%nh)*sBh;
  long cb = (long)(z/nh)*sCb + (long)(z%nh)*sCh;
  int m0 = blockIdx.y*128, n0 = blockIdx.x*128;
  __shared__ u16 As[128*32];
  __shared__ u16 Bs[128*32];
  int tid=threadIdx.x, w=tid>>6, lane=tid&63, q=lane>>4, lr=lane&15;
  int wrow=(w>>1)*64, wcol=(w&1)*64;
  int srow = tid>>2, scol = (tid&3)*8;
  const u16* ga  = Ab + (long)(m0+srow)*lda + scol;
  const u16* ga2 = Ab + (long)(m0+64+srow)*lda + scol;
  const u16* gb  = Bb + (long)(n0+srow)*ldb + scol;
  const u16* gb2 = Bb + (long)(n0+64+srow)*ldb + scol;
  u16* la  = &As[srow*32 + scol];
  u16* la2 = &As[(64+srow)*32 + scol];
  u16* lb  = &Bs[srow*32 + scol];
  u16* lb2 = &Bs[(64+srow)*32 + scol];
  f4 acc[4][4] = {};
  for(int k0=0;k0<K;k0+=32){
    gload_lds(ga, la);  gload_lds(ga2, la2);
    gload_lds(gb, lb);  gload_lds(gb2, lb2);
    ga+=32; ga2+=32; gb+=32; gb2+=32;
    __syncthreads();
    bf8 af[4], bfr[4];
    #pragma unroll
    for(int r=0;r<4;r++) af[r]  = *(const bf8*)&As[(wrow + r*16 + lr)*32 + q*8];
    #pragma unroll
    for(int t=0;t<4;t++) bfr[t] = *(const bf8*)&Bs[(wcol + t*16 + lr)*32 + q*8];
    #pragma unroll
    for(int r=0;r<4;r++)
      #pragma unroll
      for(int t=0;t<4;t++)
        acc[r][t] = __builtin_amdgcn_mfma_f32_16x16x32_bf16(af[r], bfr[t], acc[r][t], 0,0,0);
    __syncthreads();
  }
  #pragma unroll
  for(int r=0;r<4;r++){
    #pragma unroll
    for(int t=0;t<4;t++){
      #pragma unroll
      for(int e=0;e<4;e++){
        int gm = m0 + wrow + r*16 + q*4 + e;
        int gn = n0 + wcol + t*16 + lr;
        float v = acc[r][t][e]*alpha;
        if(bias) v += bias[gn];
        if(relu) v = fmaxf(v,0.f);
        if(MODE==0) C[cb + (long)gm*ldc + gn] = v;
        else if(MODE==2) C16[cb + (long)gm*ldc + gn] = f2b(v);
        else { if(gm>=rowoff) C[cb + (long)(gm-rowoff)*ldc + gn] += v; }
      }
    }
  }
}

// ======== 64x64 NT bf16 GEMM, split-K capable ========
template<int MODE>
__global__ __launch_bounds__(256)
void k_g64(const u16* __restrict__ A, const u16* __restrict__ B,
           float* __restrict__ C, u16* __restrict__ C16,
           int K, int lda, int ldb, int ldc,
           long sAb, long sAh, long sBb, long sBh, long sCb, long sCh, int nh,
           float alpha, int nx, int ksplit)
{
  int z = blockIdx.z;
  const u16* Ab = A + (long)(z/nh)*sAb + (long)(z%nh)*sAh;
  const u16* Bb = B + (long)(z/nh)*sBb + (long)(z%nh)*sBh;
  long cb = (long)(z/nh)*sCb + (long)(z%nh)*sCh;
  int bx = blockIdx.x % nx, kc = blockIdx.x / nx;
  int m0 = blockIdx.y*64, n0 = bx*64;
  int klen = K/ksplit, kbeg = kc*klen;
  __shared__ u16 As[64*32];
  __shared__ u16 Bs[64*32];
  int tid=threadIdx.x, w=tid>>6, lane=tid&63, q=lane>>4, lr=lane&15;
  int srow = tid>>2, scol = (tid&3)*8;
  const u16* ga = Ab + (long)(m0+srow)*lda + kbeg + scol;
  const u16* gb = Bb + (long)(n0+srow)*ldb + kbeg + scol;
  u16* la = &As[srow*32 + scol];
  u16* lb = &Bs[srow*32 + scol];
  f4 acc[4] = {};
  for(int kk=0;kk<klen;kk+=32){
    gload_lds(ga, la); gload_lds(gb, lb);
    ga+=32; gb+=32;
    __syncthreads();
    bf8 af = *(const bf8*)&As[(w*16 + lr)*32 + q*8];
    #pragma unroll
    for(int t=0;t<4;t++){
      bf8 bfr = *(const bf8*)&Bs[(t*16 + lr)*32 + q*8];
      acc[t] = __builtin_amdgcn_mfma_f32_16x16x32_bf16(af, bfr, acc[t], 0,0,0);
    }
    __syncthreads();
  }
  #pragma unroll
  for(int t=0;t<4;t++){
    #pragma unroll
    for(int e=0;e<4;e++){
      int gm = m0 + w*16 + q*4 + e;
      int gn = n0 + t*16 + lr;
      float v = acc[t][e]*alpha;
      if(MODE==0) C[cb + (long)gm*ldc + gn] = v;
      else if(MODE==2) C16[cb + (long)gm*ldc + gn] = f2b(v);
      else atomicAdd(&C[cb + (long)gm*ldc + gn], v);
    }
  }
}

// ======== pinv GEMM on bf16 hi/lo pairs — pipelined ping-pong staging ========
// S[m][n] = sum_k A[m][k]*B[n][k] (3-MFMA split). If Oh: Oh/Ol = na*S + nd*I.
// If TOh: TOh/TOl[gn][gm] = ta*S[gm][gn] + td*I.
__global__ __launch_bounds__(256)
void k_pg3(const u16* __restrict__ Ah, const u16* __restrict__ Al,
           const u16* __restrict__ Bh, const u16* __restrict__ Bl,
           u16* __restrict__ Oh, u16* __restrict__ Ol, float na, float nd,
           u16* __restrict__ TOh, u16* __restrict__ TOl, float ta, float td)
{
  long zo = (long)blockIdx.z*65536;
  int m0 = blockIdx.y*64, n0 = blockIdx.x*64;
  __shared__ u16 S[2][4][2048];   // [region][Ah,Al,Bh,Bl][64x32 tile]
  int tid=threadIdx.x, w=tid>>6, lane=tid&63, q=lane>>4, lr=lane&15;
  int srow=tid>>2, scol=(tid&3)*8;
  long ao = zo + (long)(m0+srow)*256 + scol;
  long bo = zo + (long)(n0+srow)*256 + scol;
  int lo = srow*32 + scol;
  int aoff = (w*16+lr)*32 + q*8;
  f4 acc[4] = {};
  auto stage = [&](int r, int c){
    gload_lds(Ah+ao+c*32, &S[r][0][lo]);
    gload_lds(Al+ao+c*32, &S[r][1][lo]);
    gload_lds(Bh+bo+c*32, &S[r][2][lo]);
    gload_lds(Bl+bo+c*32, &S[r][3][lo]);
  };
  auto compute = [&](int r){
    bf8 ah = *(const bf8*)&S[r][0][aoff];
    bf8 al = *(const bf8*)&S[r][1][aoff];
    #pragma unroll
    for(int t=0;t<4;t++){
      int boff = (t*16+lr)*32 + q*8;
      bf8 bh = *(const bf8*)&S[r][2][boff];
      bf8 bl = *(const bf8*)&S[r][3][boff];
      acc[t] = __builtin_amdgcn_mfma_f32_16x16x32_bf16(ah, bh, acc[t], 0,0,0);
      acc[t] = __builtin_amdgcn_mfma_f32_16x16x32_bf16(ah, bl, acc[t], 0,0,0);
      acc[t] = __builtin_amdgcn_mfma_f32_16x16x32_bf16(al, bh, acc[t], 0,0,0);
    }
  };
  stage(0,0);
  __syncthreads();
  #pragma unroll
  for(int c=1;c<8;c++){
    stage(c&1, c);        // prefetch into other region (overlaps compute below)
    compute((c-1)&1);     // consume previous chunk
    __syncthreads();      // all waves done with old region; drains prefetch
  }
  compute(1);
  #pragma unroll
  for(int t=0;t<4;t++){
    int gn = n0 + t*16 + lr;
    if(Oh){
      #pragma unroll
      for(int r=0;r<4;r++){
        int gm = m0 + w*16 + q*4 + r;
        float v = na*acc[t][r] + ((gm==gn)?nd:0.f);
        u16 h = f2b(v);
        long o = zo + (long)gm*256 + gn;
        Oh[o] = h; Ol[o] = f2b(v - b2f(h));
      }
    }
    if(TOh){
      us4 th, tl;
      #pragma unroll
      for(int r=0;r<4;r++){
        int gm = m0 + w*16 + q*4 + r;
        float v = ta*acc[t][r] + ((gm==gn)?td:0.f);
        u16 h = f2b(v);
        th[r] = h; tl[r] = f2b(v - b2f(h));
      }
      long o = zo + (long)gn*256 + (m0 + w*16 + q*4);
      *(us4*)&TOh[o] = th; *(us4*)&TOl[o] = tl;
    }
  }
}

// ======== softmax: wave per row, 256 cols ========
__global__ __launch_bounds__(256)
void k_smw32(float* __restrict__ X){
  long row = (long)blockIdx.x*4 + (threadIdx.x>>6);
  int lane = threadIdx.x & 63;
  float* p = X + row*256;
  float4 v = *(float4*)&p[lane*4];
  float m = fmaxf(fmaxf(v.x,v.y),fmaxf(v.z,v.w));
  for(int s=32;s;s>>=1) m = fmaxf(m, __shfl_xor(m, s));
  float e0=expf(v.x-m), e1=expf(v.y-m), e2=expf(v.z-m), e3=expf(v.w-m);
  float sum = e0+e1+e2+e3;
  for(int s=32;s;s>>=1) sum += __shfl_xor(sum, s);
  float inv = 1.f/sum;
  float4 o = {e0*inv, e1*inv, e2*inv, e3*inv};
  *(float4*)&p[lane*4] = o;
}

__global__ __launch_bounds__(256)
void k_smw16(u16* __restrict__ X){
  long row = (long)blockIdx.x*4 + (threadIdx.x>>6);
  int lane = threadIdx.x & 63;
  u16* p = X + row*256;
  us4 v = *(us4*)&p[lane*4];
  float f0=b2f(v[0]), f1=b2f(v[1]), f2=b2f(v[2]), f3=b2f(v[3]);
  float m = fmaxf(fmaxf(f0,f1),fmaxf(f2,f3));
  for(int s=32;s;s>>=1) m = fmaxf(m, __shfl_xor(m, s));
  float e0=expf(f0-m), e1=expf(f1-m), e2=expf(f2-m), e3=expf(f3-m);
  float sum = e0+e1+e2+e3;
  for(int s=32;s;s>>=1) sum += __shfl_xor(sum, s);
  float inv = 1.f/sum;
  us4 o = {f2b(e0*inv), f2b(e1*inv), f2b(e2*inv), f2b(e3*inv)};
  *(us4*)&p[lane*4] = o;
}

// ======== softmax: block per row, 4352 cols, register-resident ========
__global__ __launch_bounds__(256)
void k_smb16(u16* __restrict__ X){
  u16* p = X + (long)blockIdx.x*4352;
  int tid=threadIdx.x, lane=tid&63, w=tid>>6;
  __shared__ float xw[4], sw[4];
  float e[17];
  float m = -1e30f;
  #pragma unroll
  for(int i=0;i<17;i++){ e[i] = b2f(p[tid + i*256]); m = fmaxf(m, e[i]); }
  for(int s=32;s;s>>=1) m = fmaxf(m, __shfl_xor(m, s));
  if(lane==0) xw[w] = m;
  __syncthreads();
  m = fmaxf(fmaxf(xw[0],xw[1]), fmaxf(xw[2],xw[3]));
  float sum = 0.f;
  #pragma unroll
  for(int i=0;i<17;i++){ e[i] = expf(e[i]-m); sum += e[i]; }
  for(int s=32;s;s>>=1) sum += __shfl_xor(sum, s);
  if(lane==0) sw[w] = sum;
  __syncthreads();
  sum = sw[0]+sw[1]+sw[2]+sw[3];
  float inv = 1.f/sum;
  #pragma unroll
  for(int i=0;i<17;i++) p[tid + i*256] = f2b(e[i]*inv);
}

// weight transpose+convert: in fp32 [K][N] -> out bf16 [N][K]
__global__ void k_wT(const float* __restrict__ in, u16* __restrict__ out, int K, int N){
  int n0=blockIdx.x*32, k0=blockIdx.y*32, tid=threadIdx.x;
  __shared__ float T[32][33];
  int lr=tid&31, lc=tid>>5;
  #pragma unroll
  for(int p=0;p<4;p++) T[lc+8*p][lr] = in[(long)(k0+lc+8*p)*N + n0+lr];
  __syncthreads();
  #pragma unroll
  for(int p=0;p<4;p++) out[(long)(n0+lc+8*p)*K + k0+lr] = f2b(T[lr][lc+8*p]);
}

// v^T: qkvb16 v-section [NP][64] per (b,h) -> vT [b][h][64][NP]
__global__ __launch_bounds__(256)
void k_vT(const u16* __restrict__ qkv16, u16* __restrict__ vT){
  int t0=blockIdx.x*64, h=blockIdx.y, b=blockIdx.z, tid=threadIdx.x;
  __shared__ u16 T[64][72];
  const u16* src = qkv16 + (long)b*NP*1536 + 1024 + h*64;
  for(int s=0;s<2;s++){
    int idx=tid+s*256; int row=idx>>3, c8=(idx&7)*8;
    *(us8*)&T[row][c8] = *(const us8*)&src[(long)(t0+row)*1536 + c8];
  }
  __syncthreads();
  u16* dst = vT + ((long)(b*8+h)*64)*NP;
  int d = tid>>2, j0=(tid&3)*16;
  us8 v0,v1;
  #pragma unroll
  for(int jj=0;jj<8;jj++){ v0[jj]=T[j0+jj][d]; v1[jj]=T[j0+8+jj][d]; }
  *(us8*)&dst[(long)d*NP + t0 + j0]     = v0;
  *(us8*)&dst[(long)d*NP + t0 + j0 + 8] = v1;
}

__global__ void k_cvt16(const float* __restrict__ in, u16* __restrict__ out, long n){
  long i = (long)blockIdx.x*256 + threadIdx.x;
  if(i<n) out[i] = f2b(in[i]);
}

__global__ void k_zero(float* __restrict__ p, long n){
  long i = (long)blockIdx.x*256 + threadIdx.x;
  if(i<n) p[i] = 0.f;
}

__global__ void k_cls(const float* __restrict__ cls, float* __restrict__ seq){
  int b = blockIdx.x;
  seq[(long)b*NTOK*EMB + threadIdx.x] = cls[threadIdx.x];
}

// LayerNorm of seq into xpb bf16 with 255 zero rows at front
__global__ void k_ln_pad(const float* __restrict__ seq, u16* __restrict__ xp,
                         const float* __restrict__ g, const float* __restrict__ bb){
  int b = blockIdx.y, i = blockIdx.x, tid = threadIdx.x;
  u16* out = xp + ((long)b*NP + i)*EMB;
  if(i < PADF){ out[tid]=0; out[tid+256]=0; return; }
  const float* x = seq + ((long)b*NTOK + (i-PADF))*EMB;
  float v0 = x[tid], v1 = x[tid+256];
  __shared__ float red[256];
  red[tid]=v0+v1; __syncthreads();
  for(int s=128;s>0;s>>=1){ if(tid<s) red[tid]+=red[tid+s]; __syncthreads(); }
  float mu = red[0]*(1.0f/512.0f); __syncthreads();
  float d0=v0-mu, d1=v1-mu;
  red[tid]=d0*d0+d1*d1; __syncthreads();
  for(int s=128;s>0;s>>=1){ if(tid<s) red[tid]+=red[tid+s]; __syncthreads(); }
  float rstd = rsqrtf(red[0]*(1.0f/512.0f) + 1e-5f);
  out[tid]     = f2b(d0*rstd*g[tid]     + bb[tid]);
  out[tid+256] = f2b(d1*rstd*g[tid+256] + bb[tid+256]);
}

__global__ void k_landmarks(const u16* __restrict__ qkv, u16* __restrict__ q_l, u16* __restrict__ k_l){
  int j = blockIdx.x, h = blockIdx.y, b = blockIdx.z, d = threadIdx.x;
  const u16* base = qkv + (long)b*NP*1536 + h*64 + d;
  float sq=0.f, sk=0.f;
  for(int l=0;l<17;l++){
    long row = (long)(j*17+l)*1536;
    sq += b2f(base[row]);
    sk += b2f(base[row+512]);
  }
  long o = (((long)b*HEADS + h)*LM + j)*DH + d;
  q_l[o] = f2b(sq * (SCALE/17.0f));
  k_l[o] = f2b(sk * (1.0f/17.0f));
}

__global__ void k_pinv_norm(const float* __restrict__ A2, float* __restrict__ rmax, float* __restrict__ cmax){
  int z = blockIdx.x, tid = threadIdx.x;
  const float* X = A2 + (long)z*65536;
  float rs=0.f, cs=0.f;
  for(int j=0;j<256;j++){ rs += fabsf(X[tid*256+j]); cs += fabsf(X[j*256+tid]); }
  __shared__ float r1[256], r2[256];
  r1[tid]=rs; r2[tid]=cs; __syncthreads();
  for(int s=128;s>0;s>>=1){ if(tid<s){ r1[tid]=fmaxf(r1[tid],r1[tid+s]); r2[tid]=fmaxf(r2[tid],r2[tid+s]); } __syncthreads(); }
  if(tid==0){ rmax[z]=r1[0]; cmax[z]=r2[0]; }
}

__global__ void k_pair_init(const float* __restrict__ att2,
    const float* __restrict__ rmax, const float* __restrict__ cmax,
    u16* __restrict__ Xh, u16* __restrict__ Xl,
    u16* __restrict__ Zh, u16* __restrict__ Zl,
    u16* __restrict__ Zth, u16* __restrict__ Ztl)
{
  long zo = (long)blockIdx.z*65536;
  int i0 = blockIdx.y*64, j0 = blockIdx.x*64;
  float rm=0.f, cm=0.f;
  for(int t=0;t<16;t++){ rm=fmaxf(rm,rmax[t]); cm=fmaxf(cm,cmax[t]); }
  float inv = 1.0f/(rm*cm);
  __shared__ float T[64][68];
  int tid = threadIdx.x;
  int li = tid>>2, jc = (tid&3)*16;
  #pragma unroll
  for(int u=0;u<4;u++){
    float4 v = *(const float4*)&att2[zo + (long)(i0+li)*256 + j0 + jc + u*4];
    T[li][jc+u*4]=v.x; T[li][jc+u*4+1]=v.y; T[li][jc+u*4+2]=v.z; T[li][jc+u*4+3]=v.w;
    long o = zo + (long)(i0+li)*256 + j0 + jc + u*4;
    float vv[4] = {v.x,v.y,v.z,v.w};
    us4 xh, xl, zth, ztl;
    #pragma unroll
    for(int c=0;c<4;c++){
      u16 h = f2b(vv[c]); xh[c]=h; xl[c]=f2b(vv[c]-b2f(h));
      float zt = vv[c]*inv;
      u16 h2 = f2b(zt); zth[c]=h2; ztl[c]=f2b(zt-b2f(h2));
    }
    *(us4*)&Xh[o]=xh; *(us4*)&Xl[o]=xl; *(us4*)&Zth[o]=zth; *(us4*)&Ztl[o]=ztl;
  }
  __syncthreads();
  int lj = tid>>2, ic = (tid&3)*16;
  #pragma unroll
  for(int r=0;r<16;r++){
    float x = T[ic+r][lj]*inv;
    u16 h = f2b(x);
    long o = zo + (long)(j0+lj)*256 + i0 + ic + r;
    Zh[o]=h; Zl[o]=f2b(x-b2f(h));
  }
}

// res conv + fused bf16 convert: Qc16 = bf16(Qc + dwconv(v))
__global__ __launch_bounds__(256)
void k_rconv(const u16* __restrict__ qkv16, const float* __restrict__ resk,
             const float* __restrict__ Qin, u16* __restrict__ Qo16){
  int t0 = blockIdx.x*64, h = blockIdx.y, b = blockIdx.z;
  __shared__ float V[96*64];
  const u16* vb = qkv16 + (long)b*NP*1536 + 1024 + h*64;
  int tid = threadIdx.x;
  #pragma unroll
  for(int s=0;s<3;s++){
    int idx = tid + s*256;
    int row = idx>>3, c8 = (idx&7)*8;
    int p = t0 - 16 + row;
    if(p>=0 && p<NP){
      us8 v = *(const us8*)&vb[(long)p*1536 + c8];
      #pragma unroll
      for(int jj=0;jj<8;jj++) V[row*64+c8+jj] = b2f(v[jj]);
    } else {
      #pragma unroll
      for(int jj=0;jj<8;jj++) V[row*64+c8+jj] = 0.f;
    }
  }
  __syncthreads();
  int d = tid&63, lt = (tid>>6)*16;
  float acc[16] = {};
  #pragma unroll
  for(int s=0;s<48;s++){
    float val = V[(lt+s)*64 + d];
    #pragma unroll
    for(int j=0;j<16;j++){
      int tap = s - j;
      if(tap>=0 && tap<33) acc[j] += resk[h*33+tap]*val;
    }
  }
  #pragma unroll
  for(int j=0;j<16;j++){
    long idx = ((long)b*NP + t0 + lt + j)*EMB + h*64 + d;
    Qo16[idx] = f2b(Qin[idx] + acc[j]);
  }
}

// PPEG: 64-ch groups, 4 rows x 64 ch per block, x-split 2; grid (32, 8, 2)
__global__ __launch_bounds__(256)
void k_ppeg(const float* __restrict__ seq, float* __restrict__ out,
    const float* __restrict__ w7,const float* __restrict__ b7,
    const float* __restrict__ w5,const float* __restrict__ b5,
    const float* __restrict__ w3,const float* __restrict__ b3){
  int b = blockIdx.z, cg = blockIdx.y;
  int rp = blockIdx.x>>1, xs = blockIdx.x&1;
  int ch0 = cg*64;
  __shared__ float s7[64*49], s5[64*25], s3[64*9], sbias[64];
  int tid = threadIdx.x;
  for(int i=tid;i<64*49;i+=256) s7[i] = w7[ch0*49+i];
  for(int i=tid;i<64*25;i+=256) s5[i] = w5[ch0*25+i];
  for(int i=tid;i<64*9;i+=256)  s3[i] = w3[ch0*9+i];
  if(tid<64) sbias[tid] = b7[ch0+tid]+b5[ch0+tid]+b3[ch0+tid];
  if(cg==0 && blockIdx.x==0){
    out[(long)b*NTOK*EMB + tid]       = seq[(long)b*NTOK*EMB + tid];
    out[(long)b*NTOK*EMB + 256 + tid] = seq[(long)b*NTOK*EMB + 256 + tid];
  }
  __syncthreads();
  int c = tid & 63;
  int y = rp*4 + (tid>>6);
  const float* sbase = seq + (long)b*NTOK*EMB + EMB + (ch0 + c);
  float* obase = out + (long)b*NTOK*EMB + EMB + (ch0 + c);
  const float* W7 = &s7[c*49];
  const float* W5 = &s5[c*25];
  const float* W3 = &s3[c*9];
  float bsum = sbias[c];
  for(int xc=0;xc<4;xc++){
    int xb = xs*32 + xc*8;
    float acc[8];
    #pragma unroll
    for(int j=0;j<8;j++) acc[j] = sbase[(long)(y*64+xb+j)*EMB] + bsum;
    #pragma unroll
    for(int dy=-3;dy<=3;dy++){
      int yy = y+dy;
      if(yy<0||yy>=64) continue;
      float v[14];
      #pragma unroll
      for(int u=0;u<14;u++){
        int xx = xb + u - 3;
        v[u] = (xx>=0 && xx<64) ? sbase[(long)(yy*64+xx)*EMB] : 0.f;
      }
      #pragma unroll
      for(int dx=-3;dx<=3;dx++){
        float wsum = W7[(dy+3)*7+(dx+3)];
        if(dy>=-2&&dy<=2&&dx>=-2&&dx<=2) wsum += W5[(dy+2)*5+(dx+2)];
        if(dy>=-1&&dy<=1&&dx>=-1&&dx<=1) wsum += W3[(dy+1)*3+(dx+1)];
        #pragma unroll
        for(int j=0;j<8;j++) acc[j] += v[j+dx+3]*wsum;
      }
    }
    #pragma unroll
    for(int j=0;j<8;j++) obase[(long)(y*64+xb+j)*EMB] = acc[j];
  }
}

__global__ void k_final_ln(const float* __restrict__ seq, const float* __restrict__ g,
                           const float* __restrict__ bb, float* __restrict__ out){
  int b = blockIdx.x, tid = threadIdx.x;
  const float* x = seq + (long)b*NTOK*EMB;
  float v0 = x[tid], v1 = x[tid+256];
  __shared__ float red[256];
  red[tid]=v0+v1; __syncthreads();
  for(int s=128;s>0;s>>=1){ if(tid<s) red[tid]+=red[tid+s]; __syncthreads(); }
  float mu = red[0]*(1.0f/512.0f); __syncthreads();
  float d0=v0-mu, d1=v1-mu;
  red[tid]=d0*d0+d1*d1; __syncthreads();
  for(int s=128;s>0;s>>=1){ if(tid<s) red[tid]+=red[tid+s]; __syncthreads(); }
  float rstd = rsqrtf(red[0]*(1.0f/512.0f) + 1e-5f);
  out[b*512+tid]     = d0*rstd*g[tid]     + bb[tid];
  out[b*512+tid+256] = d1*rstd*g[tid+256] + bb[tid+256];
}

// ---------------- host ----------------
extern "C" void kernel_launch(void* const* d_in, const int* in_sizes, int n_in,
                              void* d_out, int out_size, void* d_ws, size_t ws_size,
                              hipStream_t stream) {
  const float* in[24];
  for(int i=0;i<24;i++) in[i] = (const float*)d_in[i];

  float* W = (float*)d_ws;
  size_t off = 0;
  float* seqA = W+off; off += 4195328;        // 2*4097*512
  float* seqB = W+off; off += 4195328;
  float* att2 = W+off; off += 1048576;        // 16*65536
  float* Qc   = W+off; off += 4456448;        // 2*4352*512
  float* avbT = W+off; off += 262144;         // 16*64*256
  u16* xpb    = (u16*)(W+off); off += 2228224;  // 2*4352*512 u16
  u16* qkvb16 = (u16*)(W+off); off += 6684672;  // 2*4352*1536 u16
  u16* vT16   = (u16*)(W+off); off += 2228224;
  u16* q_l16  = (u16*)(W+off); off += 131072;   // 16*256*64 u16
  u16* k_l16  = (u16*)(W+off); off += 131072;
  u16* sc16   = (u16*)(W+off); off += 8912896;  // 16*256*4352 u16
  u16* avbT16 = (u16*)(W+off); off += 131072;
  u16* zavT16 = (u16*)(W+off); off += 131072;
  u16* Qc16   = (u16*)(W+off); off += 2228224;
  u16* qkvwT1 = (u16*)(W+off); off += 393216;   // 1536*512 u16
  u16* qkvwT2 = (u16*)(W+off); off += 393216;
  u16* outwT1 = (u16*)(W+off); off += 131072;   // 512*512 u16
  u16* outwT2 = (u16*)(W+off); off += 131072;
  u16* pairs  = (u16*)(W+off); off += 9437184;  // 18*16*65536 u16
  float* rmax = W+off; off += 16;
  float* cmax = W+off; off += 16;
  if (ws_size < off*sizeof(float)) return;

  // h16 + wfc1T aliased inside sc16 (sc16 first written later, in attention())
  u16* h16   = sc16;                  // 8388608 u16
  u16* wfc1T = sc16 + 8388608;        // 524288 u16

  const long PB = 1048576;  // 16*65536
  u16 *Xh=pairs, *Xl=pairs+PB;
  u16 *Z0h=pairs+2*PB, *Z0l=pairs+3*PB, *Z0th=pairs+4*PB, *Z0tl=pairs+5*PB;
  u16 *Z1h=pairs+6*PB, *Z1l=pairs+7*PB, *Z1th=pairs+8*PB, *Z1tl=pairs+9*PB;
  u16 *Ph=pairs+10*PB, *Pl=pairs+11*PB;
  u16 *Tth=pairs+12*PB, *Ttl=pairs+13*PB;
  u16 *Uth=pairs+14*PB, *Utl=pairs+15*PB;
  u16 *Vth=pairs+16*PB, *Vtl=pairs+17*PB;

  // weight conversions/transposes
  k_cvt16<<<32768,256,0,stream>>>(in[0], h16, 8388608L);
  k_wT<<<dim3(16,32),256,0,stream>>>(in[1],  wfc1T, 1024, 512);
  k_wT<<<dim3(48,16),256,0,stream>>>(in[6],  qkvwT1, 512, 1536);
  k_wT<<<dim3(48,16),256,0,stream>>>(in[18], qkvwT2, 512, 1536);
  k_wT<<<dim3(16,16),256,0,stream>>>(in[7],  outwT1, 512, 512);
  k_wT<<<dim3(16,16),256,0,stream>>>(in[19], outwT2, 512, 512);

  // fc1 + cls
  k_g128<0><<<dim3(4,32,2),256,0,stream>>>(h16, wfc1T, seqA+EMB, nullptr,
      1024, 1024,1024,512, 4194304L,0, 0,0, (long)NTOK*EMB,0, 1, 1.0f, in[2], 1, 0);
  k_cls<<<2,512,0,stream>>>(in[3], seqA);

  auto attention = [&](float* seq, const float* lng,const float* lnb,
                       const u16* qkvwT, const u16* outwT, const float* outb, const float* resk){
    k_ln_pad<<<dim3(NP,2),256,0,stream>>>(seq, xpb, lng, lnb);
    k_g128<2><<<dim3(12,34,2),256,0,stream>>>(xpb, qkvwT, nullptr, qkvb16,
        512, 512,512,1536, (long)NP*512,0, 0,0, (long)NP*1536,0, 1, 1.0f, nullptr, 0, 0);
    k_landmarks<<<dim3(LM,HEADS,2),64,0,stream>>>(qkvb16, q_l16, k_l16);
    k_vT<<<dim3(68,8,2),256,0,stream>>>(qkvb16, vT16);
    // attn2 = softmax(q_l @ k_l^T)  (fp32 scores for pinv)
    k_g128<0><<<dim3(2,2,16),256,0,stream>>>(q_l16, k_l16, att2, nullptr,
        64, 64,64,256, 0,16384, 0,16384, 0,65536, 16, 1.0f, nullptr, 0, 0);
    k_smw32<<<1024,256,0,stream>>>(att2);
    // pinv on bf16 pairs
    k_pinv_norm<<<16,256,0,stream>>>(att2, rmax, cmax);
    k_pair_init<<<dim3(4,4,16),256,0,stream>>>(att2, rmax, cmax, Xh,Xl, Z0h,Z0l, Z0th,Z0tl);
    dim3 pgrid(4,4,16);
    for(int it=0; it<6; it++){
      u16 *Zh_=(it&1)?Z1h:Z0h, *Zl_=(it&1)?Z1l:Z0l, *Zth_=(it&1)?Z1th:Z0th, *Ztl_=(it&1)?Z1tl:Z0tl;
      u16 *Nh_=(it&1)?Z0h:Z1h, *Nl_=(it&1)?Z0l:Z1l, *Nth_=(it&1)?Z0th:Z1th, *Ntl_=(it&1)?Z0tl:Z1tl;
      // P = X@Z (normal) ; Tt = (7I - P)^T (transposed)
      k_pg3<<<pgrid,256,0,stream>>>(Xh,Xl, Zth_,Ztl_, Ph,Pl,1.0f,0.f, Tth,Ttl,-1.0f,7.f);
      // Ut = (15I - P@T)^T
      k_pg3<<<pgrid,256,0,stream>>>(Ph,Pl, Tth,Ttl, nullptr,nullptr,0.f,0.f, Uth,Utl,-1.0f,15.f);
      // Vt = (13I - P@U)^T
      k_pg3<<<pgrid,256,0,stream>>>(Ph,Pl, Uth,Utl, nullptr,nullptr,0.f,0.f, Vth,Vtl,-1.0f,13.f);
      // Znew = 0.25 Z@V (normal; + transposed except last iter)
      if(it<5) k_pg3<<<pgrid,256,0,stream>>>(Zh_,Zl_, Vth,Vtl, Nh_,Nl_,0.25f,0.f, Nth_,Ntl_,0.25f,0.f);
      else     k_pg3<<<pgrid,256,0,stream>>>(Zh_,Zl_, Vth,Vtl, Nh_,Nl_,0.25f,0.f, nullptr,nullptr,0.f,0.f);
    }
    // attn3 scores = q_l @ k^T -> sc16 (bf16)
    k_g128<2><<<dim3(34,2,16),256,0,stream>>>(q_l16, qkvb16+512, nullptr, sc16,
        64, 64,1536,4352, 131072L,16384, (long)NP*1536,64, 8L*LM*NP,(long)LM*NP, 8, 1.0f, nullptr, 0, 0);
    k_smb16<<<4096,256,0,stream>>>(sc16);
    // avbT = v^T @ attn3_sm^T (split-K atomic)
    k_zero<<<1024,256,0,stream>>>(avbT, 262144L);
    k_g64<3><<<dim3(4*17,1,16),256,0,stream>>>(vT16, sc16, avbT, nullptr,
        4352, 4352,4352,256, 2228224L,278528L, 8L*LM*NP,(long)LM*NP, 131072L,16384L, 8, 1.0f, 4, 17);
    k_cvt16<<<1024,256,0,stream>>>(avbT, avbT16, 262144L);
    // zavT = avbT @ Z^T  -> bf16
    k_g64<2><<<dim3(4,1,16),256,0,stream>>>(avbT16, Z0h, nullptr, zavT16,
        256, 256,256,256, 0,16384L, 0,65536L, 0,16384L, 16, 1.0f, 4, 1);
    // attn1 scores = SCALE * q @ k_l^T -> sc16
    k_g128<2><<<dim3(2,34,16),256,0,stream>>>(qkvb16, k_l16, nullptr, sc16,
        64, 1536,64,256, (long)NP*1536,64, 131072L,16384L, 8L*NP*LM,(long)NP*LM, 8, SCALE, nullptr, 0, 0);
    k_smw16<<<17408,256,0,stream>>>(sc16);
    // Qc = attn1_sm @ zav   (per-head 64-col blocks)
    k_g64<0><<<dim3(1,68,16),256,0,stream>>>(sc16, zavT16, Qc, nullptr,
        256, 256,256,512, 8L*NP*LM,(long)NP*LM, 131072L,16384L, (long)NP*512,64, 8, 1.0f, 1, 1);
    // res conv fused with bf16 convert
    k_rconv<<<dim3(68,8,2),256,0,stream>>>(qkvb16, resk, Qc, Qc16);
    // out proj + residual add into seq
    k_g128<3><<<dim3(4,34,2),256,0,stream>>>(Qc16, outwT, seq, nullptr,
        512, 512,512,512, (long)NP*512,0, 0,0, (long)NTOK*EMB,0, 1, 1.0f, outb, 0, PADF);
  };

  attention(seqA, in[4], in[5], qkvwT1, outwT1, in[8], in[9]);
  k_ppeg<<<dim3(32,8,2),256,0,stream>>>(seqA, seqB, in[10],in[11],in[12],in[13],in[14],in[15]);
  attention(seqB, in[16], in[17], qkvwT2, outwT2, in[20], in[21]);
  k_final_ln<<<2,256,0,stream>>>(seqB, in[22], in[23], (float*)d_out);
}